// Round 1
// baseline (302.981 us; speedup 1.0000x reference)
//
#include <hip/hip_runtime.h>
#include <stdint.h>

#define B_ 4
#define N_ 2048
#define M_ 2048
#define F_ 512
#define H_ 8
#define D_ 64

typedef __bf16 bf16x8 __attribute__((ext_vector_type(8)));
typedef float f32x4 __attribute__((ext_vector_type(4)));

__device__ inline ushort f32_bf16(float f) {
    union { float f; uint32_t u; } v; v.f = f;
    uint32_t r = v.u + 0x7FFFu + ((v.u >> 16) & 1u);
    return (ushort)(r >> 16);
}

// ---------------- LayerNorm: 18432 rows (x: 8192, pos_emb: 2048, context: 8192) ----
__global__ __launch_bounds__(128) void ln_kernel(
    const float* __restrict__ x, const float* __restrict__ ctx, const float* __restrict__ pos,
    const float* __restrict__ lnw, const float* __restrict__ lnb,
    const float* __restrict__ lncw, const float* __restrict__ lncb,
    ushort* __restrict__ xn, ushort* __restrict__ kn, ushort* __restrict__ cn)
{
    int r = blockIdx.x;
    const float* src; ushort* dst; const float* w; const float* bp;
    if (r < B_ * N_) {
        src = x + (size_t)r * F_; dst = xn + (size_t)r * F_; w = lnw; bp = lnb;
    } else if (r < B_ * N_ + M_) {
        int rr = r - B_ * N_;
        src = pos + (size_t)rr * F_; dst = kn + (size_t)rr * F_; w = lnw; bp = lnb;
    } else {
        int rr = r - (B_ * N_ + M_);
        src = ctx + (size_t)rr * F_; dst = cn + (size_t)rr * F_; w = lncw; bp = lncb;
    }
    int tid = threadIdx.x;
    int wave = tid >> 6, lane = tid & 63;
    float4 v = reinterpret_cast<const float4*>(src)[tid];
    float s = v.x + v.y + v.z + v.w;
    float sq = v.x * v.x + v.y * v.y + v.z * v.z + v.w * v.w;
    #pragma unroll
    for (int mask = 1; mask < 64; mask <<= 1) {
        s += __shfl_xor(s, mask, 64);
        sq += __shfl_xor(sq, mask, 64);
    }
    __shared__ float red[4];
    if (lane == 0) { red[wave * 2] = s; red[wave * 2 + 1] = sq; }
    __syncthreads();
    float S = red[0] + red[2], SQ = red[1] + red[3];
    float mean = S * (1.0f / F_);
    float var = SQ * (1.0f / F_) - mean * mean;
    float rstd = rsqrtf(var + 1e-5f);
    float4 wv = reinterpret_cast<const float4*>(w)[tid];
    float4 bv = reinterpret_cast<const float4*>(bp)[tid];
    ushort4 o;
    o.x = f32_bf16((v.x - mean) * rstd * wv.x + bv.x);
    o.y = f32_bf16((v.y - mean) * rstd * wv.y + bv.y);
    o.z = f32_bf16((v.z - mean) * rstd * wv.z + bv.z);
    o.w = f32_bf16((v.w - mean) * rstd * wv.w + bv.w);
    reinterpret_cast<ushort4*>(dst)[tid] = o;
}

// ---------------- Weight transpose + f32->bf16: WT[n][k] = W[k][n] --------------
__global__ __launch_bounds__(256) void wtrans_kernel(
    const float* __restrict__ Wq, const float* __restrict__ Wk,
    const float* __restrict__ Wv, const float* __restrict__ Wo,
    ushort* __restrict__ WqT, ushort* __restrict__ WkT,
    ushort* __restrict__ WvT, ushort* __restrict__ WoT)
{
    const float* W; ushort* WT;
    switch (blockIdx.z) {
        case 0: W = Wq; WT = WqT; break;
        case 1: W = Wk; WT = WkT; break;
        case 2: W = Wv; WT = WvT; break;
        default: W = Wo; WT = WoT; break;
    }
    __shared__ float tile[32][33];
    int tx = threadIdx.x, ty = threadIdx.y;   // 32 x 8
    int n0 = blockIdx.x * 32, k0 = blockIdx.y * 32;
    #pragma unroll
    for (int j = 0; j < 4; ++j)
        tile[ty + j * 8][tx] = W[(size_t)(k0 + ty + j * 8) * F_ + n0 + tx];
    __syncthreads();
    #pragma unroll
    for (int j = 0; j < 4; ++j)
        WT[(size_t)(n0 + ty + j * 8) * F_ + k0 + tx] = f32_bf16(tile[tx][ty + j * 8]);
}

// ---------------- bf16 MFMA GEMM: C[R][512] = A[R][512] * B, BT[n][k] given ------
template<bool BIAS, bool OUTF32>
__global__ __launch_bounds__(256) void gemm_kernel(
    const ushort* __restrict__ A, const ushort* __restrict__ BT,
    const float* __restrict__ bias, void* __restrict__ Cout)
{
    __shared__ ushort As[128][72];
    __shared__ ushort Bs[128][72];
    int tid = threadIdx.x;
    int row0 = blockIdx.y * 128;
    int col0 = blockIdx.x * 128;
    int wave = tid >> 6, lane = tid & 63;
    int wm = wave >> 1, wn = wave & 1;
    f32x4 acc[4][4] = {};

    for (int k0 = 0; k0 < F_; k0 += 64) {
        #pragma unroll
        for (int p = 0; p < 4; ++p) {
            int c = tid + p * 256;
            int r = c >> 3, kc = (c & 7) * 8;
            *reinterpret_cast<uint4*>(&As[r][kc]) =
                *reinterpret_cast<const uint4*>(&A[(size_t)(row0 + r) * F_ + k0 + kc]);
            *reinterpret_cast<uint4*>(&Bs[r][kc]) =
                *reinterpret_cast<const uint4*>(&BT[(size_t)(col0 + r) * F_ + k0 + kc]);
        }
        __syncthreads();
        #pragma unroll
        for (int kt = 0; kt < 2; ++kt) {
            int lrow = lane & 15, lk = kt * 32 + (lane >> 4) * 8;
            bf16x8 af[4], bfr[4];
            #pragma unroll
            for (int mt = 0; mt < 4; ++mt)
                af[mt] = *reinterpret_cast<const bf16x8*>(&As[wm * 64 + mt * 16 + lrow][lk]);
            #pragma unroll
            for (int nt = 0; nt < 4; ++nt)
                bfr[nt] = *reinterpret_cast<const bf16x8*>(&Bs[wn * 64 + nt * 16 + lrow][lk]);
            #pragma unroll
            for (int mt = 0; mt < 4; ++mt)
                #pragma unroll
                for (int nt = 0; nt < 4; ++nt)
                    acc[mt][nt] = __builtin_amdgcn_mfma_f32_16x16x32_bf16(
                        af[mt], bfr[nt], acc[mt][nt], 0, 0, 0);
        }
        __syncthreads();
    }

    int lr4 = (lane >> 4) * 4, lc = lane & 15;
    #pragma unroll
    for (int mt = 0; mt < 4; ++mt) {
        #pragma unroll
        for (int nt = 0; nt < 4; ++nt) {
            int ccol = col0 + wn * 64 + nt * 16 + lc;
            float bv = BIAS ? bias[ccol] : 0.0f;
            #pragma unroll
            for (int j = 0; j < 4; ++j) {
                int crow = row0 + wm * 64 + mt * 16 + lr4 + j;
                float val = acc[mt][nt][j] + bv;
                if (OUTF32)
                    reinterpret_cast<float*>(Cout)[(size_t)crow * F_ + ccol] = val;
                else
                    reinterpret_cast<ushort*>(Cout)[(size_t)crow * F_ + ccol] = f32_bf16(val);
            }
        }
    }
}

// ---------------- V transpose: vT[(b*8+h)*64+d][m] = v[b*M+m][h*64+d] ------------
__global__ __launch_bounds__(256) void vtrans_kernel(
    const ushort* __restrict__ v, ushort* __restrict__ vT)
{
    int bh = blockIdx.y;               // b*8+h
    int b = bh >> 3, h = bh & 7;
    int m0 = blockIdx.x * 64;
    __shared__ ushort tile[64][72];
    int tid = threadIdx.x;
    int r = tid >> 2, c8 = (tid & 3) * 16;
    const ushort* vrow = v + (size_t)(b * M_ + m0 + r) * F_ + h * 64 + c8;
    *reinterpret_cast<uint4*>(&tile[r][c8]) = *reinterpret_cast<const uint4*>(&vrow[0]);
    *reinterpret_cast<uint4*>(&tile[r][c8 + 8]) = *reinterpret_cast<const uint4*>(&vrow[8]);
    __syncthreads();
    int d = tid >> 2, mc = (tid & 3) * 16;
    union { ushort u[8]; uint4 q; } p0, p1;
    #pragma unroll
    for (int i = 0; i < 8; ++i) p0.u[i] = tile[mc + i][d];
    #pragma unroll
    for (int i = 0; i < 8; ++i) p1.u[i] = tile[mc + 8 + i][d];
    ushort* orow = vT + ((size_t)bh * 64 + d) * M_ + m0 + mc;
    *reinterpret_cast<uint4*>(&orow[0]) = p0.q;
    *reinterpret_cast<uint4*>(&orow[8]) = p1.q;
}

// ---------------- Flash attention ------------------------------------------------
__global__ __launch_bounds__(256) void attn_kernel(
    const ushort* __restrict__ q,   // [B*N][512]
    const ushort* __restrict__ k,   // [M][512]  (batch-independent)
    const ushort* __restrict__ vT,  // [B*H*64][M]
    ushort* __restrict__ o)         // [B*N][512]
{
    __shared__ ushort p_lds[4][16][40];
    int wave = threadIdx.x >> 6, lane = threadIdx.x & 63;
    int bh = blockIdx.y;
    int b = bh >> 3, h = bh & 7;
    int q0 = blockIdx.x * 64 + wave * 16;
    int lrow = lane & 15, lk8 = (lane >> 4) * 8;
    int r4 = lane >> 4;

    bf16x8 qf0 = *reinterpret_cast<const bf16x8*>(
        &q[(size_t)(b * N_ + q0 + lrow) * F_ + h * 64 + lk8]);
    bf16x8 qf1 = *reinterpret_cast<const bf16x8*>(
        &q[(size_t)(b * N_ + q0 + lrow) * F_ + h * 64 + 32 + lk8]);

    float m_run[4], l_run[4];
    f32x4 oacc[4] = {};
    #pragma unroll
    for (int j = 0; j < 4; ++j) { m_run[j] = -1e30f; l_run[j] = 0.0f; }

    const ushort* vbase = vT + (size_t)bh * 64 * M_;

    for (int m0 = 0; m0 < M_; m0 += 32) {
        bf16x8 kf0a = *reinterpret_cast<const bf16x8*>(
            &k[(size_t)(m0 + lrow) * F_ + h * 64 + lk8]);
        bf16x8 kf0b = *reinterpret_cast<const bf16x8*>(
            &k[(size_t)(m0 + lrow) * F_ + h * 64 + 32 + lk8]);
        bf16x8 kf1a = *reinterpret_cast<const bf16x8*>(
            &k[(size_t)(m0 + 16 + lrow) * F_ + h * 64 + lk8]);
        bf16x8 kf1b = *reinterpret_cast<const bf16x8*>(
            &k[(size_t)(m0 + 16 + lrow) * F_ + h * 64 + 32 + lk8]);

        f32x4 z = {0.0f, 0.0f, 0.0f, 0.0f};
        f32x4 s0 = __builtin_amdgcn_mfma_f32_16x16x32_bf16(qf0, kf0a, z, 0, 0, 0);
        s0 = __builtin_amdgcn_mfma_f32_16x16x32_bf16(qf1, kf0b, s0, 0, 0, 0);
        f32x4 s1 = __builtin_amdgcn_mfma_f32_16x16x32_bf16(qf0, kf1a, z, 0, 0, 0);
        s1 = __builtin_amdgcn_mfma_f32_16x16x32_bf16(qf1, kf1b, s1, 0, 0, 0);

        float pmax[4], mnew[4], resc[4], rs[4];
        #pragma unroll
        for (int j = 0; j < 4; ++j) {
            s0[j] *= 0.125f; s1[j] *= 0.125f;
            pmax[j] = fmaxf(s0[j], s1[j]);
        }
        #pragma unroll
        for (int j = 0; j < 4; ++j) {
            #pragma unroll
            for (int mask = 1; mask < 16; mask <<= 1)
                pmax[j] = fmaxf(pmax[j], __shfl_xor(pmax[j], mask, 64));
        }
        #pragma unroll
        for (int j = 0; j < 4; ++j) {
            mnew[j] = fmaxf(m_run[j], pmax[j]);
            resc[j] = __expf(m_run[j] - mnew[j]);
            float p0 = __expf(s0[j] - mnew[j]);
            float p1 = __expf(s1[j] - mnew[j]);
            s0[j] = p0; s1[j] = p1;
            rs[j] = p0 + p1;
            m_run[j] = mnew[j];
        }
        #pragma unroll
        for (int j = 0; j < 4; ++j) {
            #pragma unroll
            for (int mask = 1; mask < 16; mask <<= 1)
                rs[j] += __shfl_xor(rs[j], mask, 64);
            l_run[j] = l_run[j] * resc[j] + rs[j];
        }
        #pragma unroll
        for (int t = 0; t < 4; ++t)
            #pragma unroll
            for (int j = 0; j < 4; ++j)
                oacc[t][j] *= resc[j];

        // P (C/D layout) -> LDS -> A-layout fragment
        #pragma unroll
        for (int j = 0; j < 4; ++j) {
            p_lds[wave][r4 * 4 + j][lrow] = f32_bf16(s0[j]);
            p_lds[wave][r4 * 4 + j][16 + lrow] = f32_bf16(s1[j]);
        }
        bf16x8 pf = *reinterpret_cast<const bf16x8*>(&p_lds[wave][lrow][lk8]);

        #pragma unroll
        for (int t = 0; t < 4; ++t) {
            bf16x8 vf = *reinterpret_cast<const bf16x8*>(
                &vbase[(size_t)(t * 16 + lrow) * M_ + m0 + lk8]);
            oacc[t] = __builtin_amdgcn_mfma_f32_16x16x32_bf16(pf, vf, oacc[t], 0, 0, 0);
        }
    }

    float inv[4];
    #pragma unroll
    for (int j = 0; j < 4; ++j) inv[j] = 1.0f / l_run[j];
    #pragma unroll
    for (int t = 0; t < 4; ++t)
        #pragma unroll
        for (int j = 0; j < 4; ++j)
            o[(size_t)(b * N_ + q0 + r4 * 4 + j) * F_ + h * 64 + t * 16 + lrow] =
                f32_bf16(oacc[t][j] * inv[j]);
}

// ---------------- Launch ---------------------------------------------------------
extern "C" void kernel_launch(void* const* d_in, const int* in_sizes, int n_in,
                              void* d_out, int out_size, void* d_ws, size_t ws_size,
                              hipStream_t stream) {
    const float* x    = (const float*)d_in[0];
    const float* ctx  = (const float*)d_in[1];
    const float* pos  = (const float*)d_in[2];
    const float* lnw  = (const float*)d_in[3];
    const float* lnb  = (const float*)d_in[4];
    const float* lncw = (const float*)d_in[5];
    const float* lncb = (const float*)d_in[6];
    const float* Wq   = (const float*)d_in[7];
    const float* Wk   = (const float*)d_in[8];
    const float* Wv   = (const float*)d_in[9];
    const float* Wo   = (const float*)d_in[10];
    const float* bout = (const float*)d_in[11];
    float* out = (float*)d_out;

    char* ws = (char*)d_ws;
    ushort* xn  = (ushort*)(ws + 0);         // 8 MB  [8192][512]
    ushort* cn  = (ushort*)(ws + 8388608);   // 8 MB  [8192][512]
    ushort* kn  = (ushort*)(ws + 16777216);  // 2 MB  [2048][512]
    ushort* WqT = (ushort*)(ws + 18874368);  // 512 KB
    ushort* WkT = (ushort*)(ws + 19398656);
    ushort* WvT = (ushort*)(ws + 19922944);
    ushort* WoT = (ushort*)(ws + 20447232);
    ushort* qb  = (ushort*)(ws + 20971520);  // 8 MB  [8192][512]
    ushort* kb  = (ushort*)(ws + 29360128);  // 2 MB  [2048][512]
    ushort* vb  = (ushort*)(ws + 31457280);  // 8 MB  [8192][512]
    ushort* vTb = (ushort*)(ws + 39845888);  // 8 MB  [32*64][2048]
    ushort* ao  = (ushort*)(ws + 48234496);  // 8 MB  [8192][512]

    hipLaunchKernelGGL(ln_kernel, dim3(B_ * N_ + M_ + B_ * M_), dim3(128), 0, stream,
                       x, ctx, pos, lnw, lnb, lncw, lncb, xn, kn, cn);
    hipLaunchKernelGGL(wtrans_kernel, dim3(16, 16, 4), dim3(32, 8), 0, stream,
                       Wq, Wk, Wv, Wo, WqT, WkT, WvT, WoT);
    hipLaunchKernelGGL((gemm_kernel<false, false>), dim3(4, 64), dim3(256), 0, stream,
                       xn, WqT, nullptr, (void*)qb);
    hipLaunchKernelGGL((gemm_kernel<false, false>), dim3(4, 16), dim3(256), 0, stream,
                       kn, WkT, nullptr, (void*)kb);
    hipLaunchKernelGGL((gemm_kernel<false, false>), dim3(4, 64), dim3(256), 0, stream,
                       cn, WvT, nullptr, (void*)vb);
    hipLaunchKernelGGL(vtrans_kernel, dim3(32, 32), dim3(256), 0, stream, vb, vTb);
    hipLaunchKernelGGL(attn_kernel, dim3(32, 32), dim3(256), 0, stream, qb, kb, vTb, ao);
    hipLaunchKernelGGL((gemm_kernel<true, true>), dim3(4, 64), dim3(256), 0, stream,
                       ao, WoT, bout, (void*)out);
}

// Round 7
// 198.196 us; speedup vs baseline: 1.5287x; 1.5287x over previous
//
#include <hip/hip_runtime.h>
#include <stdint.h>

#define B_ 4
#define N_ 2048
#define M_ 2048
#define F_ 512
#define H_ 8
#define D_ 64

typedef __bf16 bf16x8 __attribute__((ext_vector_type(8)));
typedef float f32x4 __attribute__((ext_vector_type(4)));
typedef float f32x16 __attribute__((ext_vector_type(16)));

__device__ inline ushort f32_bf16(float f) {
    union { float f; uint32_t u; } v; v.f = f;
    uint32_t r = v.u + 0x7FFFu + ((v.u >> 16) & 1u);
    return (ushort)(r >> 16);
}

// ---------------- LayerNorm: 18432 rows (x: 8192, pos_emb: 2048, context: 8192) ----
__global__ __launch_bounds__(128) void ln_kernel(
    const float* __restrict__ x, const float* __restrict__ ctx, const float* __restrict__ pos,
    const float* __restrict__ lnw, const float* __restrict__ lnb,
    const float* __restrict__ lncw, const float* __restrict__ lncb,
    ushort* __restrict__ xn, ushort* __restrict__ kn, ushort* __restrict__ cn)
{
    int r = blockIdx.x;
    const float* src; ushort* dst; const float* w; const float* bp;
    if (r < B_ * N_) {
        src = x + (size_t)r * F_; dst = xn + (size_t)r * F_; w = lnw; bp = lnb;
    } else if (r < B_ * N_ + M_) {
        int rr = r - B_ * N_;
        src = pos + (size_t)rr * F_; dst = kn + (size_t)rr * F_; w = lnw; bp = lnb;
    } else {
        int rr = r - (B_ * N_ + M_);
        src = ctx + (size_t)rr * F_; dst = cn + (size_t)rr * F_; w = lncw; bp = lncb;
    }
    int tid = threadIdx.x;
    int wave = tid >> 6, lane = tid & 63;
    float4 v = reinterpret_cast<const float4*>(src)[tid];
    float s = v.x + v.y + v.z + v.w;
    float sq = v.x * v.x + v.y * v.y + v.z * v.z + v.w * v.w;
    #pragma unroll
    for (int mask = 1; mask < 64; mask <<= 1) {
        s += __shfl_xor(s, mask, 64);
        sq += __shfl_xor(sq, mask, 64);
    }
    __shared__ float red[4];
    if (lane == 0) { red[wave * 2] = s; red[wave * 2 + 1] = sq; }
    __syncthreads();
    float S = red[0] + red[2], SQ = red[1] + red[3];
    float mean = S * (1.0f / F_);
    float var = SQ * (1.0f / F_) - mean * mean;
    float rstd = rsqrtf(var + 1e-5f);
    float4 wv = reinterpret_cast<const float4*>(w)[tid];
    float4 bv = reinterpret_cast<const float4*>(bp)[tid];
    ushort4 o;
    o.x = f32_bf16((v.x - mean) * rstd * wv.x + bv.x);
    o.y = f32_bf16((v.y - mean) * rstd * wv.y + bv.y);
    o.z = f32_bf16((v.z - mean) * rstd * wv.z + bv.z);
    o.w = f32_bf16((v.w - mean) * rstd * wv.w + bv.w);
    reinterpret_cast<ushort4*>(dst)[tid] = o;
}

// ---------------- Weight transpose + f32->bf16: WT[n][k] = W[k][n] --------------
__global__ __launch_bounds__(256) void wtrans_kernel(
    const float* __restrict__ Wq, const float* __restrict__ Wk,
    const float* __restrict__ Wv, const float* __restrict__ Wo,
    ushort* __restrict__ WqT, ushort* __restrict__ WkT,
    ushort* __restrict__ WvT, ushort* __restrict__ WoT)
{
    const float* W; ushort* WT;
    switch (blockIdx.z) {
        case 0: W = Wq; WT = WqT; break;
        case 1: W = Wk; WT = WkT; break;
        case 2: W = Wv; WT = WvT; break;
        default: W = Wo; WT = WoT; break;
    }
    __shared__ float tile[32][33];
    int tx = threadIdx.x, ty = threadIdx.y;   // 32 x 8
    int n0 = blockIdx.x * 32, k0 = blockIdx.y * 32;
    #pragma unroll
    for (int j = 0; j < 4; ++j)
        tile[ty + j * 8][tx] = W[(size_t)(k0 + ty + j * 8) * F_ + n0 + tx];
    __syncthreads();
    #pragma unroll
    for (int j = 0; j < 4; ++j)
        WT[(size_t)(n0 + ty + j * 8) * F_ + k0 + tx] = f32_bf16(tile[tx][ty + j * 8]);
}

// ---------------- bf16 MFMA GEMM: C[R][512] = A[R][512] * B, BT[n][k] given ------
template<bool BIAS, bool OUTF32>
__global__ __launch_bounds__(256) void gemm_kernel(
    const ushort* __restrict__ A, const ushort* __restrict__ BT,
    const float* __restrict__ bias, void* __restrict__ Cout)
{
    __shared__ ushort As[128][72];
    __shared__ ushort Bs[128][72];
    int tid = threadIdx.x;
    int row0 = blockIdx.y * 128;
    int col0 = blockIdx.x * 128;
    int wave = tid >> 6, lane = tid & 63;
    int wm = wave >> 1, wn = wave & 1;
    f32x4 acc[4][4] = {};

    for (int k0 = 0; k0 < F_; k0 += 64) {
        #pragma unroll
        for (int p = 0; p < 4; ++p) {
            int c = tid + p * 256;
            int r = c >> 3, kc = (c & 7) * 8;
            *reinterpret_cast<uint4*>(&As[r][kc]) =
                *reinterpret_cast<const uint4*>(&A[(size_t)(row0 + r) * F_ + k0 + kc]);
            *reinterpret_cast<uint4*>(&Bs[r][kc]) =
                *reinterpret_cast<const uint4*>(&BT[(size_t)(col0 + r) * F_ + k0 + kc]);
        }
        __syncthreads();
        #pragma unroll
        for (int kt = 0; kt < 2; ++kt) {
            int lrow = lane & 15, lk = kt * 32 + (lane >> 4) * 8;
            bf16x8 af[4], bfr[4];
            #pragma unroll
            for (int mt = 0; mt < 4; ++mt)
                af[mt] = *reinterpret_cast<const bf16x8*>(&As[wm * 64 + mt * 16 + lrow][lk]);
            #pragma unroll
            for (int nt = 0; nt < 4; ++nt)
                bfr[nt] = *reinterpret_cast<const bf16x8*>(&Bs[wn * 64 + nt * 16 + lrow][lk]);
            #pragma unroll
            for (int mt = 0; mt < 4; ++mt)
                #pragma unroll
                for (int nt = 0; nt < 4; ++nt)
                    acc[mt][nt] = __builtin_amdgcn_mfma_f32_16x16x32_bf16(
                        af[mt], bfr[nt], acc[mt][nt], 0, 0, 0);
        }
        __syncthreads();
    }

    int lr4 = (lane >> 4) * 4, lc = lane & 15;
    #pragma unroll
    for (int mt = 0; mt < 4; ++mt) {
        #pragma unroll
        for (int nt = 0; nt < 4; ++nt) {
            int ccol = col0 + wn * 64 + nt * 16 + lc;
            float bv = BIAS ? bias[ccol] : 0.0f;
            #pragma unroll
            for (int j = 0; j < 4; ++j) {
                int crow = row0 + wm * 64 + mt * 16 + lr4 + j;
                float val = acc[mt][nt][j] + bv;
                if (OUTF32)
                    reinterpret_cast<float*>(Cout)[(size_t)crow * F_ + ccol] = val;
                else
                    reinterpret_cast<ushort*>(Cout)[(size_t)crow * F_ + ccol] = f32_bf16(val);
            }
        }
    }
}

// ---------------- V transpose: vT[(b*8+h)*64+d][m] = v[b*M+m][h*64+d] ------------
__global__ __launch_bounds__(256) void vtrans_kernel(
    const ushort* __restrict__ v, ushort* __restrict__ vT)
{
    int bh = blockIdx.y;               // b*8+h
    int b = bh >> 3, h = bh & 7;
    int m0 = blockIdx.x * 64;
    __shared__ ushort tile[64][72];
    int tid = threadIdx.x;
    int r = tid >> 2, c8 = (tid & 3) * 16;
    const ushort* vrow = v + (size_t)(b * M_ + m0 + r) * F_ + h * 64 + c8;
    *reinterpret_cast<uint4*>(&tile[r][c8]) = *reinterpret_cast<const uint4*>(&vrow[0]);
    *reinterpret_cast<uint4*>(&tile[r][c8 + 8]) = *reinterpret_cast<const uint4*>(&vrow[8]);
    __syncthreads();
    int d = tid >> 2, mc = (tid & 3) * 16;
    union { ushort u[8]; uint4 q; } p0, p1;
    #pragma unroll
    for (int i = 0; i < 8; ++i) p0.u[i] = tile[mc + i][d];
    #pragma unroll
    for (int i = 0; i < 8; ++i) p1.u[i] = tile[mc + 8 + i][d];
    ushort* orow = vT + ((size_t)bh * 64 + d) * M_ + m0 + mc;
    *reinterpret_cast<uint4*>(&orow[0]) = p0.q;
    *reinterpret_cast<uint4*>(&orow[8]) = p1.q;
}

// ---------------- Flash attention, 32x32x16 swapped-QK^T structure ----------------
// Per wave: 32 q-rows. Swapped QK: S^T = mfma(K_frag, Q_frag) -> lane holds 16
// scores (k-quads) of q-row (lane&31); partner lane (^32) holds the other quads.
// Softmax fully in-register; P->A-frag via v_cvt_pk_bf16_f32 + v_permlane32_swap.
#define MAKE_PA(dst, p, ss) do {                                               \
    uint32_t w0_, w1_, w2_, w3_;                                               \
    asm("v_cvt_pk_bf16_f32 %0, %1, %2" : "=v"(w0_) : "v"(p[8*(ss)+0]), "v"(p[8*(ss)+1])); \
    asm("v_cvt_pk_bf16_f32 %0, %1, %2" : "=v"(w1_) : "v"(p[8*(ss)+2]), "v"(p[8*(ss)+3])); \
    asm("v_cvt_pk_bf16_f32 %0, %1, %2" : "=v"(w2_) : "v"(p[8*(ss)+4]), "v"(p[8*(ss)+5])); \
    asm("v_cvt_pk_bf16_f32 %0, %1, %2" : "=v"(w3_) : "v"(p[8*(ss)+6]), "v"(p[8*(ss)+7])); \
    asm("v_permlane32_swap_b32 %0, %1" : "+v"(w0_), "+v"(w2_));                \
    asm("v_permlane32_swap_b32 %0, %1" : "+v"(w1_), "+v"(w3_));                \
    union { uint32_t w[4]; bf16x8 v; } u_;                                     \
    u_.w[0] = w0_; u_.w[1] = w1_; u_.w[2] = w2_; u_.w[3] = w3_;                \
    dst = u_.v;                                                                \
} while (0)

__global__ __launch_bounds__(256) void attn_kernel(
    const ushort* __restrict__ q,   // [B*N][512] bf16
    const ushort* __restrict__ k,   // [M][512]   bf16 (batch-independent)
    const ushort* __restrict__ vT,  // [B*H*64][M] bf16
    ushort* __restrict__ o)         // [B*N][512] bf16
{
    const int wave = threadIdx.x >> 6, lane = threadIdx.x & 63;
    const int l31 = lane & 31, g = lane >> 5;
    const int bh = blockIdx.y, b = bh >> 3, h = bh & 7;
    const int q0 = blockIdx.x * 128 + wave * 32;

    // Q fragments (hoisted): qf[ds] = Q[q0+l31][ds*16 + g*8 .. +7]
    bf16x8 qf[4];
    const ushort* qrow = q + (size_t)(b * N_ + q0 + l31) * F_ + h * 64 + g * 8;
    #pragma unroll
    for (int ds = 0; ds < 4; ++ds)
        qf[ds] = *reinterpret_cast<const bf16x8*>(qrow + ds * 16);

    float m_run = -1e30f, l_run = 0.0f;
    f32x16 oacc[2];
    #pragma unroll
    for (int hh = 0; hh < 2; ++hh)
        #pragma unroll
        for (int j = 0; j < 16; ++j) oacc[hh][j] = 0.0f;

    const ushort* kbase = k + h * 64 + g * 8;
    const ushort* vbase = vT + ((size_t)bh * 64 + l31) * M_ + g * 8;
    const float c1 = 0.18033688f;        // 0.125 * log2(e)
    const float log2e = 1.4426950f;

    for (int m0 = 0; m0 < M_; m0 += 64) {
        // ---- QK^T (swapped): sA = K[m0..m0+31] x Q, sB = K[m0+32..m0+63] x Q
        f32x16 sA, sB;
        #pragma unroll
        for (int j = 0; j < 16; ++j) { sA[j] = 0.0f; sB[j] = 0.0f; }
        const ushort* k0p = kbase + (size_t)(m0 + l31) * F_;
        const ushort* k1p = k0p + 32 * F_;
        #pragma unroll
        for (int ds = 0; ds < 4; ++ds) {
            bf16x8 kfa = *reinterpret_cast<const bf16x8*>(k0p + ds * 16);
            sA = __builtin_amdgcn_mfma_f32_32x32x16_bf16(kfa, qf[ds], sA, 0, 0, 0);
        }
        #pragma unroll
        for (int ds = 0; ds < 4; ++ds) {
            bf16x8 kfb = *reinterpret_cast<const bf16x8*>(k1p + ds * 16);
            sB = __builtin_amdgcn_mfma_f32_32x32x16_bf16(kfb, qf[ds], sB, 0, 0, 0);
        }

        // ---- row max (in-register + one cross shfl)
        float pm = sA[0];
        #pragma unroll
        for (int j = 1; j < 16; ++j) pm = fmaxf(pm, sA[j]);
        #pragma unroll
        for (int j = 0; j < 16; ++j) pm = fmaxf(pm, sB[j]);
        pm = fmaxf(pm, __shfl_xor(pm, 32, 64));
        pm *= 0.125f;

        // ---- defer-max rescale (rare)
        if (!__all(pm <= m_run + 8.0f)) {
            float mnew = fmaxf(m_run, pm);
            float resc = __builtin_amdgcn_exp2f((m_run - mnew) * log2e);
            m_run = mnew;
            l_run *= resc;
            // broadcast resc (lives at lane == q-row) to oacc layout rows
            float rf[16];
            #pragma unroll
            for (int j = 0; j < 16; ++j)
                rf[j] = __shfl(resc, 8 * (j >> 2) + 4 * g + (j & 3), 64);
            #pragma unroll
            for (int hh = 0; hh < 2; ++hh)
                #pragma unroll
                for (int j = 0; j < 16; ++j) oacc[hh][j] *= rf[j];
        }

        // ---- exp + row sum
        float c2 = -m_run * log2e;
        float p0f[16], p1f[16];
        float rs = 0.0f;
        #pragma unroll
        for (int j = 0; j < 16; ++j) {
            p0f[j] = __builtin_amdgcn_exp2f(fmaf(sA[j], c1, c2)); rs += p0f[j];
        }
        #pragma unroll
        for (int j = 0; j < 16; ++j) {
            p1f[j] = __builtin_amdgcn_exp2f(fmaf(sB[j], c1, c2)); rs += p1f[j];
        }
        rs += __shfl_xor(rs, 32, 64);
        l_run += rs;

        // ---- P -> A-fragments (cvt_pk + permlane32_swap, no LDS)
        bf16x8 pa[4];
        MAKE_PA(pa[0], p0f, 0);
        MAKE_PA(pa[1], p0f, 1);
        MAKE_PA(pa[2], p1f, 0);
        MAKE_PA(pa[3], p1f, 1);

        // ---- PV: oacc[hh] += P[32q x 64k] @ V[64k x 32d]
        const ushort* vp = vbase + m0;
        #pragma unroll
        for (int hh = 0; hh < 2; ++hh) {
            const ushort* vph = vp + (size_t)hh * 32 * M_;
            #pragma unroll
            for (int s = 0; s < 4; ++s) {
                bf16x8 vf = *reinterpret_cast<const bf16x8*>(vph + s * 16);
                oacc[hh] = __builtin_amdgcn_mfma_f32_32x32x16_bf16(pa[s], vf, oacc[hh], 0, 0, 0);
            }
        }
    }

    // ---- final normalization + store
    float linv = 1.0f / l_run;
    float rf[16];
    #pragma unroll
    for (int j = 0; j < 16; ++j)
        rf[j] = __shfl(linv, 8 * (j >> 2) + 4 * g + (j & 3), 64);
    #pragma unroll
    for (int hh = 0; hh < 2; ++hh)
        #pragma unroll
        for (int j = 0; j < 16; ++j) {
            int qr = (j & 3) + 8 * (j >> 2) + 4 * g;
            o[(size_t)(b * N_ + q0 + qr) * F_ + h * 64 + hh * 32 + l31] =
                f32_bf16(oacc[hh][j] * rf[j]);
        }
}

// ---------------- Launch ---------------------------------------------------------
extern "C" void kernel_launch(void* const* d_in, const int* in_sizes, int n_in,
                              void* d_out, int out_size, void* d_ws, size_t ws_size,
                              hipStream_t stream) {
    const float* x    = (const float*)d_in[0];
    const float* ctx  = (const float*)d_in[1];
    const float* pos  = (const float*)d_in[2];
    const float* lnw  = (const float*)d_in[3];
    const float* lnb  = (const float*)d_in[4];
    const float* lncw = (const float*)d_in[5];
    const float* lncb = (const float*)d_in[6];
    const float* Wq   = (const float*)d_in[7];
    const float* Wk   = (const float*)d_in[8];
    const float* Wv   = (const float*)d_in[9];
    const float* Wo   = (const float*)d_in[10];
    const float* bout = (const float*)d_in[11];
    float* out = (float*)d_out;

    char* ws = (char*)d_ws;
    ushort* xn  = (ushort*)(ws + 0);         // 8 MB  [8192][512]
    ushort* cn  = (ushort*)(ws + 8388608);   // 8 MB  [8192][512]
    ushort* kn  = (ushort*)(ws + 16777216);  // 2 MB  [2048][512]
    ushort* WqT = (ushort*)(ws + 18874368);  // 512 KB
    ushort* WkT = (ushort*)(ws + 19398656);
    ushort* WvT = (ushort*)(ws + 19922944);
    ushort* WoT = (ushort*)(ws + 20447232);
    ushort* qb  = (ushort*)(ws + 20971520);  // 8 MB  [8192][512]
    ushort* kb  = (ushort*)(ws + 29360128);  // 2 MB  [2048][512]
    ushort* vb  = (ushort*)(ws + 31457280);  // 8 MB  [8192][512]
    ushort* vTb = (ushort*)(ws + 39845888);  // 8 MB  [32*64][2048]
    ushort* ao  = (ushort*)(ws + 48234496);  // 8 MB  [8192][512]

    hipLaunchKernelGGL(ln_kernel, dim3(B_ * N_ + M_ + B_ * M_), dim3(128), 0, stream,
                       x, ctx, pos, lnw, lnb, lncw, lncb, xn, kn, cn);
    hipLaunchKernelGGL(wtrans_kernel, dim3(16, 16, 4), dim3(32, 8), 0, stream,
                       Wq, Wk, Wv, Wo, WqT, WkT, WvT, WoT);
    hipLaunchKernelGGL((gemm_kernel<false, false>), dim3(4, 64), dim3(256), 0, stream,
                       xn, WqT, nullptr, (void*)qb);
    hipLaunchKernelGGL((gemm_kernel<false, false>), dim3(4, 16), dim3(256), 0, stream,
                       kn, WkT, nullptr, (void*)kb);
    hipLaunchKernelGGL((gemm_kernel<false, false>), dim3(4, 64), dim3(256), 0, stream,
                       cn, WvT, nullptr, (void*)vb);
    hipLaunchKernelGGL(vtrans_kernel, dim3(32, 32), dim3(256), 0, stream, vb, vTb);
    hipLaunchKernelGGL(attn_kernel, dim3(16, 32), dim3(256), 0, stream, qb, kb, vTb, ao);
    hipLaunchKernelGGL((gemm_kernel<true, true>), dim3(4, 64), dim3(256), 0, stream,
                       ao, WoT, bout, (void*)out);
}

// Round 8
// 193.787 us; speedup vs baseline: 1.5635x; 1.0228x over previous
//
#include <hip/hip_runtime.h>
#include <stdint.h>

#define B_ 4
#define N_ 2048
#define M_ 2048
#define F_ 512
#define H_ 8
#define D_ 64

typedef __bf16 bf16x8 __attribute__((ext_vector_type(8)));
typedef float f32x4 __attribute__((ext_vector_type(4)));
typedef float f32x16 __attribute__((ext_vector_type(16)));

__device__ inline ushort f32_bf16(float f) {
    union { float f; uint32_t u; } v; v.f = f;
    uint32_t r = v.u + 0x7FFFu + ((v.u >> 16) & 1u);
    return (ushort)(r >> 16);
}

// ---------------- LayerNorm: 18432 rows (x: 8192, pos_emb: 2048, context: 8192) ----
__global__ __launch_bounds__(128) void ln_kernel(
    const float* __restrict__ x, const float* __restrict__ ctx, const float* __restrict__ pos,
    const float* __restrict__ lnw, const float* __restrict__ lnb,
    const float* __restrict__ lncw, const float* __restrict__ lncb,
    ushort* __restrict__ xn, ushort* __restrict__ kn, ushort* __restrict__ cn)
{
    int r = blockIdx.x;
    const float* src; ushort* dst; const float* w; const float* bp;
    if (r < B_ * N_) {
        src = x + (size_t)r * F_; dst = xn + (size_t)r * F_; w = lnw; bp = lnb;
    } else if (r < B_ * N_ + M_) {
        int rr = r - B_ * N_;
        src = pos + (size_t)rr * F_; dst = kn + (size_t)rr * F_; w = lnw; bp = lnb;
    } else {
        int rr = r - (B_ * N_ + M_);
        src = ctx + (size_t)rr * F_; dst = cn + (size_t)rr * F_; w = lncw; bp = lncb;
    }
    int tid = threadIdx.x;
    int wave = tid >> 6, lane = tid & 63;
    float4 v = reinterpret_cast<const float4*>(src)[tid];
    float s = v.x + v.y + v.z + v.w;
    float sq = v.x * v.x + v.y * v.y + v.z * v.z + v.w * v.w;
    #pragma unroll
    for (int mask = 1; mask < 64; mask <<= 1) {
        s += __shfl_xor(s, mask, 64);
        sq += __shfl_xor(sq, mask, 64);
    }
    __shared__ float red[4];
    if (lane == 0) { red[wave * 2] = s; red[wave * 2 + 1] = sq; }
    __syncthreads();
    float S = red[0] + red[2], SQ = red[1] + red[3];
    float mean = S * (1.0f / F_);
    float var = SQ * (1.0f / F_) - mean * mean;
    float rstd = rsqrtf(var + 1e-5f);
    float4 wv = reinterpret_cast<const float4*>(w)[tid];
    float4 bv = reinterpret_cast<const float4*>(bp)[tid];
    ushort4 o;
    o.x = f32_bf16((v.x - mean) * rstd * wv.x + bv.x);
    o.y = f32_bf16((v.y - mean) * rstd * wv.y + bv.y);
    o.z = f32_bf16((v.z - mean) * rstd * wv.z + bv.z);
    o.w = f32_bf16((v.w - mean) * rstd * wv.w + bv.w);
    reinterpret_cast<ushort4*>(dst)[tid] = o;
}

// ---------------- Weight transpose + f32->bf16: WT[n][k] = W[k][n] --------------
__global__ __launch_bounds__(256) void wtrans_kernel(
    const float* __restrict__ Wq, const float* __restrict__ Wk,
    const float* __restrict__ Wv, const float* __restrict__ Wo,
    ushort* __restrict__ WqT, ushort* __restrict__ WkT,
    ushort* __restrict__ WvT, ushort* __restrict__ WoT)
{
    const float* W; ushort* WT;
    switch (blockIdx.z) {
        case 0: W = Wq; WT = WqT; break;
        case 1: W = Wk; WT = WkT; break;
        case 2: W = Wv; WT = WvT; break;
        default: W = Wo; WT = WoT; break;
    }
    __shared__ float tile[32][33];
    int tx = threadIdx.x, ty = threadIdx.y;   // 32 x 8
    int n0 = blockIdx.x * 32, k0 = blockIdx.y * 32;
    #pragma unroll
    for (int j = 0; j < 4; ++j)
        tile[ty + j * 8][tx] = W[(size_t)(k0 + ty + j * 8) * F_ + n0 + tx];
    __syncthreads();
    #pragma unroll
    for (int j = 0; j < 4; ++j)
        WT[(size_t)(n0 + ty + j * 8) * F_ + k0 + tx] = f32_bf16(tile[tx][ty + j * 8]);
}

// ---------------- bf16 MFMA GEMM: C[R][512] = A[R][512] * B, BT[n][k] given ------
template<bool BIAS, bool OUTF32>
__global__ __launch_bounds__(256) void gemm_kernel(
    const ushort* __restrict__ A, const ushort* __restrict__ BT,
    const float* __restrict__ bias, void* __restrict__ Cout)
{
    __shared__ ushort As[128][72];
    __shared__ ushort Bs[128][72];
    int tid = threadIdx.x;
    int row0 = blockIdx.y * 128;
    int col0 = blockIdx.x * 128;
    int wave = tid >> 6, lane = tid & 63;
    int wm = wave >> 1, wn = wave & 1;
    f32x4 acc[4][4] = {};

    for (int k0 = 0; k0 < F_; k0 += 64) {
        #pragma unroll
        for (int p = 0; p < 4; ++p) {
            int c = tid + p * 256;
            int r = c >> 3, kc = (c & 7) * 8;
            *reinterpret_cast<uint4*>(&As[r][kc]) =
                *reinterpret_cast<const uint4*>(&A[(size_t)(row0 + r) * F_ + k0 + kc]);
            *reinterpret_cast<uint4*>(&Bs[r][kc]) =
                *reinterpret_cast<const uint4*>(&BT[(size_t)(col0 + r) * F_ + k0 + kc]);
        }
        __syncthreads();
        #pragma unroll
        for (int kt = 0; kt < 2; ++kt) {
            int lrow = lane & 15, lk = kt * 32 + (lane >> 4) * 8;
            bf16x8 af[4], bfr[4];
            #pragma unroll
            for (int mt = 0; mt < 4; ++mt)
                af[mt] = *reinterpret_cast<const bf16x8*>(&As[wm * 64 + mt * 16 + lrow][lk]);
            #pragma unroll
            for (int nt = 0; nt < 4; ++nt)
                bfr[nt] = *reinterpret_cast<const bf16x8*>(&Bs[wn * 64 + nt * 16 + lrow][lk]);
            #pragma unroll
            for (int mt = 0; mt < 4; ++mt)
                #pragma unroll
                for (int nt = 0; nt < 4; ++nt)
                    acc[mt][nt] = __builtin_amdgcn_mfma_f32_16x16x32_bf16(
                        af[mt], bfr[nt], acc[mt][nt], 0, 0, 0);
        }
        __syncthreads();
    }

    int lr4 = (lane >> 4) * 4, lc = lane & 15;
    #pragma unroll
    for (int mt = 0; mt < 4; ++mt) {
        #pragma unroll
        for (int nt = 0; nt < 4; ++nt) {
            int ccol = col0 + wn * 64 + nt * 16 + lc;
            float bv = BIAS ? bias[ccol] : 0.0f;
            #pragma unroll
            for (int j = 0; j < 4; ++j) {
                int crow = row0 + wm * 64 + mt * 16 + lr4 + j;
                float val = acc[mt][nt][j] + bv;
                if (OUTF32)
                    reinterpret_cast<float*>(Cout)[(size_t)crow * F_ + ccol] = val;
                else
                    reinterpret_cast<ushort*>(Cout)[(size_t)crow * F_ + ccol] = f32_bf16(val);
            }
        }
    }
}

// ---------------- V transpose: vT[(b*8+h)*64+d][m] = v[b*M+m][h*64+d] ------------
__global__ __launch_bounds__(256) void vtrans_kernel(
    const ushort* __restrict__ v, ushort* __restrict__ vT)
{
    int bh = blockIdx.y;               // b*8+h
    int b = bh >> 3, h = bh & 7;
    int m0 = blockIdx.x * 64;
    __shared__ ushort tile[64][72];
    int tid = threadIdx.x;
    int r = tid >> 2, c8 = (tid & 3) * 16;
    const ushort* vrow = v + (size_t)(b * M_ + m0 + r) * F_ + h * 64 + c8;
    *reinterpret_cast<uint4*>(&tile[r][c8]) = *reinterpret_cast<const uint4*>(&vrow[0]);
    *reinterpret_cast<uint4*>(&tile[r][c8 + 8]) = *reinterpret_cast<const uint4*>(&vrow[8]);
    __syncthreads();
    int d = tid >> 2, mc = (tid & 3) * 16;
    union { ushort u[8]; uint4 q; } p0, p1;
    #pragma unroll
    for (int i = 0; i < 8; ++i) p0.u[i] = tile[mc + i][d];
    #pragma unroll
    for (int i = 0; i < 8; ++i) p1.u[i] = tile[mc + 8 + i][d];
    ushort* orow = vT + ((size_t)bh * 64 + d) * M_ + m0 + mc;
    *reinterpret_cast<uint4*>(&orow[0]) = p0.q;
    *reinterpret_cast<uint4*>(&orow[8]) = p1.q;
}

// ---------------- Flash attention, 32x32x16 swapped-QK^T + register prefetch ------
// Per wave: 32 q-rows. Swapped QK: S^T = mfma(K_frag, Q_frag) -> lane holds 16
// scores (k-quads) of q-row (lane&31); partner lane (^32) holds the other quads.
// Softmax fully in-register; P->A-frag via v_cvt_pk_bf16_f32 + v_permlane32_swap.
// K/V register-double-buffered: tile t+1 loads issue before tile t compute
// (T14 async-split, in-register) so L2 latency hides under MFMA+softmax.
#define MAKE_PA(dst, p, ss) do {                                               \
    uint32_t w0_, w1_, w2_, w3_;                                               \
    asm("v_cvt_pk_bf16_f32 %0, %1, %2" : "=v"(w0_) : "v"(p[8*(ss)+0]), "v"(p[8*(ss)+1])); \
    asm("v_cvt_pk_bf16_f32 %0, %1, %2" : "=v"(w1_) : "v"(p[8*(ss)+2]), "v"(p[8*(ss)+3])); \
    asm("v_cvt_pk_bf16_f32 %0, %1, %2" : "=v"(w2_) : "v"(p[8*(ss)+4]), "v"(p[8*(ss)+5])); \
    asm("v_cvt_pk_bf16_f32 %0, %1, %2" : "=v"(w3_) : "v"(p[8*(ss)+6]), "v"(p[8*(ss)+7])); \
    asm("v_permlane32_swap_b32 %0, %1" : "+v"(w0_), "+v"(w2_));                \
    asm("v_permlane32_swap_b32 %0, %1" : "+v"(w1_), "+v"(w3_));                \
    union { uint32_t w[4]; bf16x8 v; } u_;                                     \
    u_.w[0] = w0_; u_.w[1] = w1_; u_.w[2] = w2_; u_.w[3] = w3_;                \
    dst = u_.v;                                                                \
} while (0)

// Load K (two 32-row halves) and V (8 frags) for tile starting at mb.
#define LOADT(KA, KB, VV, mb) do {                                             \
    const ushort* _k0 = kbase + (size_t)((mb) + l31) * F_;                     \
    const ushort* _k1 = _k0 + 32 * F_;                                         \
    _Pragma("unroll")                                                          \
    for (int ds_ = 0; ds_ < 4; ++ds_) {                                        \
        KA[ds_] = *reinterpret_cast<const bf16x8*>(_k0 + ds_ * 16);            \
        KB[ds_] = *reinterpret_cast<const bf16x8*>(_k1 + ds_ * 16);            \
    }                                                                          \
    const ushort* _vp = vbase + (mb);                                          \
    _Pragma("unroll")                                                          \
    for (int s_ = 0; s_ < 8; ++s_)                                             \
        VV[s_] = *reinterpret_cast<const bf16x8*>(                             \
            _vp + (size_t)(s_ >> 2) * 32 * M_ + (s_ & 3) * 16);                \
} while (0)

// One 64-wide K/V tile: QK^T, online softmax, PV. Uses preloaded KA/KB/VV.
#define COMPUTET(KA, KB, VV) do {                                              \
    f32x16 sA, sB;                                                             \
    _Pragma("unroll")                                                          \
    for (int j = 0; j < 16; ++j) { sA[j] = 0.0f; sB[j] = 0.0f; }               \
    _Pragma("unroll")                                                          \
    for (int ds_ = 0; ds_ < 4; ++ds_) {                                        \
        sA = __builtin_amdgcn_mfma_f32_32x32x16_bf16(KA[ds_], qf[ds_], sA, 0, 0, 0); \
        sB = __builtin_amdgcn_mfma_f32_32x32x16_bf16(KB[ds_], qf[ds_], sB, 0, 0, 0); \
    }                                                                          \
    float pm = sA[0];                                                          \
    _Pragma("unroll")                                                          \
    for (int j = 1; j < 16; ++j) pm = fmaxf(pm, sA[j]);                        \
    _Pragma("unroll")                                                          \
    for (int j = 0; j < 16; ++j) pm = fmaxf(pm, sB[j]);                        \
    pm = fmaxf(pm, __shfl_xor(pm, 32, 64));                                    \
    pm *= 0.125f;                                                              \
    if (!__all(pm <= m_run + 8.0f)) {                                          \
        float mnew = fmaxf(m_run, pm);                                         \
        float resc = __builtin_amdgcn_exp2f((m_run - mnew) * log2e);           \
        m_run = mnew;                                                          \
        l_run *= resc;                                                         \
        float rf_[16];                                                         \
        _Pragma("unroll")                                                      \
        for (int j = 0; j < 16; ++j)                                           \
            rf_[j] = __shfl(resc, 8 * (j >> 2) + 4 * g + (j & 3), 64);         \
        _Pragma("unroll")                                                      \
        for (int hh = 0; hh < 2; ++hh)                                         \
            _Pragma("unroll")                                                  \
            for (int j = 0; j < 16; ++j) oacc[hh][j] *= rf_[j];                \
    }                                                                          \
    float c2 = -m_run * log2e;                                                 \
    float p0f[16], p1f[16];                                                    \
    float rs = 0.0f;                                                           \
    _Pragma("unroll")                                                          \
    for (int j = 0; j < 16; ++j) {                                             \
        p0f[j] = __builtin_amdgcn_exp2f(fmaf(sA[j], c1, c2)); rs += p0f[j];    \
    }                                                                          \
    _Pragma("unroll")                                                          \
    for (int j = 0; j < 16; ++j) {                                             \
        p1f[j] = __builtin_amdgcn_exp2f(fmaf(sB[j], c1, c2)); rs += p1f[j];    \
    }                                                                          \
    rs += __shfl_xor(rs, 32, 64);                                              \
    l_run += rs;                                                               \
    bf16x8 pa[4];                                                              \
    MAKE_PA(pa[0], p0f, 0);                                                    \
    MAKE_PA(pa[1], p0f, 1);                                                    \
    MAKE_PA(pa[2], p1f, 0);                                                    \
    MAKE_PA(pa[3], p1f, 1);                                                    \
    _Pragma("unroll")                                                          \
    for (int hh = 0; hh < 2; ++hh)                                             \
        _Pragma("unroll")                                                      \
        for (int s_ = 0; s_ < 4; ++s_)                                         \
            oacc[hh] = __builtin_amdgcn_mfma_f32_32x32x16_bf16(                \
                pa[s_], VV[hh * 4 + s_], oacc[hh], 0, 0, 0);                   \
} while (0)

__global__ __launch_bounds__(256) void attn_kernel(
    const ushort* __restrict__ q,   // [B*N][512] bf16
    const ushort* __restrict__ k,   // [M][512]   bf16 (batch-independent)
    const ushort* __restrict__ vT,  // [B*H*64][M] bf16
    ushort* __restrict__ o)         // [B*N][512] bf16
{
    const int wave = threadIdx.x >> 6, lane = threadIdx.x & 63;
    const int l31 = lane & 31, g = lane >> 5;
    const int bh = blockIdx.y, b = bh >> 3, h = bh & 7;
    const int q0 = blockIdx.x * 128 + wave * 32;

    // Q fragments (hoisted): qf[ds] = Q[q0+l31][ds*16 + g*8 .. +7]
    bf16x8 qf[4];
    const ushort* qrow = q + (size_t)(b * N_ + q0 + l31) * F_ + h * 64 + g * 8;
    #pragma unroll
    for (int ds = 0; ds < 4; ++ds)
        qf[ds] = *reinterpret_cast<const bf16x8*>(qrow + ds * 16);

    float m_run = -1e30f, l_run = 0.0f;
    f32x16 oacc[2];
    #pragma unroll
    for (int hh = 0; hh < 2; ++hh)
        #pragma unroll
        for (int j = 0; j < 16; ++j) oacc[hh][j] = 0.0f;

    const ushort* kbase = k + h * 64 + g * 8;
    const ushort* vbase = vT + ((size_t)bh * 64 + l31) * M_ + g * 8;
    const float c1 = 0.18033688f;        // 0.125 * log2(e)
    const float log2e = 1.4426950f;

    // Register double-buffer: A holds current tile, B the prefetched one.
    bf16x8 kaA[4], kbA[4], vvA[8];
    bf16x8 kaB[4], kbB[4], vvB[8];
    LOADT(kaA, kbA, vvA, 0);

    for (int m0 = 0; m0 < M_; m0 += 128) {
        LOADT(kaB, kbB, vvB, m0 + 64);      // prefetch t+1 (issues before compute)
        COMPUTET(kaA, kbA, vvA);            // compute t
        // Final iteration prefetches 64 rows past K/V (stays inside d_ws;
        // values never consumed — deterministic and harmless).
        LOADT(kaA, kbA, vvA, m0 + 128);     // prefetch t+2
        COMPUTET(kaB, kbB, vvB);            // compute t+1
    }

    // ---- final normalization + store
    float linv = 1.0f / l_run;
    float rf[16];
    #pragma unroll
    for (int j = 0; j < 16; ++j)
        rf[j] = __shfl(linv, 8 * (j >> 2) + 4 * g + (j & 3), 64);
    #pragma unroll
    for (int hh = 0; hh < 2; ++hh)
        #pragma unroll
        for (int j = 0; j < 16; ++j) {
            int qr = (j & 3) + 8 * (j >> 2) + 4 * g;
            o[(size_t)(b * N_ + q0 + qr) * F_ + h * 64 + hh * 32 + l31] =
                f32_bf16(oacc[hh][j] * rf[j]);
        }
}

// ---------------- Launch ---------------------------------------------------------
extern "C" void kernel_launch(void* const* d_in, const int* in_sizes, int n_in,
                              void* d_out, int out_size, void* d_ws, size_t ws_size,
                              hipStream_t stream) {
    const float* x    = (const float*)d_in[0];
    const float* ctx  = (const float*)d_in[1];
    const float* pos  = (const float*)d_in[2];
    const float* lnw  = (const float*)d_in[3];
    const float* lnb  = (const float*)d_in[4];
    const float* lncw = (const float*)d_in[5];
    const float* lncb = (const float*)d_in[6];
    const float* Wq   = (const float*)d_in[7];
    const float* Wk   = (const float*)d_in[8];
    const float* Wv   = (const float*)d_in[9];
    const float* Wo   = (const float*)d_in[10];
    const float* bout = (const float*)d_in[11];
    float* out = (float*)d_out;

    char* ws = (char*)d_ws;
    ushort* xn  = (ushort*)(ws + 0);         // 8 MB  [8192][512]
    ushort* cn  = (ushort*)(ws + 8388608);   // 8 MB  [8192][512]
    ushort* kn  = (ushort*)(ws + 16777216);  // 2 MB  [2048][512]
    ushort* WqT = (ushort*)(ws + 18874368);  // 512 KB
    ushort* WkT = (ushort*)(ws + 19398656);
    ushort* WvT = (ushort*)(ws + 19922944);
    ushort* WoT = (ushort*)(ws + 20447232);
    ushort* qb  = (ushort*)(ws + 20971520);  // 8 MB  [8192][512]
    ushort* kb  = (ushort*)(ws + 29360128);  // 2 MB  [2048][512]
    ushort* vb  = (ushort*)(ws + 31457280);  // 8 MB  [8192][512]
    ushort* vTb = (ushort*)(ws + 39845888);  // 8 MB  [32*64][2048]
    ushort* ao  = (ushort*)(ws + 48234496);  // 8 MB  [8192][512]

    hipLaunchKernelGGL(ln_kernel, dim3(B_ * N_ + M_ + B_ * M_), dim3(128), 0, stream,
                       x, ctx, pos, lnw, lnb, lncw, lncb, xn, kn, cn);
    hipLaunchKernelGGL(wtrans_kernel, dim3(16, 16, 4), dim3(32, 8), 0, stream,
                       Wq, Wk, Wv, Wo, WqT, WkT, WvT, WoT);
    hipLaunchKernelGGL((gemm_kernel<false, false>), dim3(4, 64), dim3(256), 0, stream,
                       xn, WqT, nullptr, (void*)qb);
    hipLaunchKernelGGL((gemm_kernel<false, false>), dim3(4, 16), dim3(256), 0, stream,
                       kn, WkT, nullptr, (void*)kb);
    hipLaunchKernelGGL((gemm_kernel<false, false>), dim3(4, 64), dim3(256), 0, stream,
                       cn, WvT, nullptr, (void*)vb);
    hipLaunchKernelGGL(vtrans_kernel, dim3(32, 32), dim3(256), 0, stream, vb, vTb);
    hipLaunchKernelGGL(attn_kernel, dim3(16, 32), dim3(256), 0, stream, qb, kb, vTb, ao);
    hipLaunchKernelGGL((gemm_kernel<true, true>), dim3(4, 64), dim3(256), 0, stream,
                       ao, WoT, bout, (void*)out);
}

// Round 9
// 152.062 us; speedup vs baseline: 1.9925x; 1.2744x over previous
//
#include <hip/hip_runtime.h>
#include <stdint.h>

#define B_ 4
#define N_ 2048
#define M_ 2048
#define F_ 512
#define H_ 8
#define D_ 64

typedef __bf16 bf16x8 __attribute__((ext_vector_type(8)));
typedef float f32x4 __attribute__((ext_vector_type(4)));
typedef float f32x16 __attribute__((ext_vector_type(16)));

__device__ inline ushort f32_bf16(float f) {
    union { float f; uint32_t u; } v; v.f = f;
    uint32_t r = v.u + 0x7FFFu + ((v.u >> 16) & 1u);
    return (ushort)(r >> 16);
}

// ---------------- LayerNorm: 18432 rows (x: 8192, pos_emb: 2048, context: 8192) ----
__global__ __launch_bounds__(128) void ln_kernel(
    const float* __restrict__ x, const float* __restrict__ ctx, const float* __restrict__ pos,
    const float* __restrict__ lnw, const float* __restrict__ lnb,
    const float* __restrict__ lncw, const float* __restrict__ lncb,
    ushort* __restrict__ xn, ushort* __restrict__ kn, ushort* __restrict__ cn)
{
    int r = blockIdx.x;
    const float* src; ushort* dst; const float* w; const float* bp;
    if (r < B_ * N_) {
        src = x + (size_t)r * F_; dst = xn + (size_t)r * F_; w = lnw; bp = lnb;
    } else if (r < B_ * N_ + M_) {
        int rr = r - B_ * N_;
        src = pos + (size_t)rr * F_; dst = kn + (size_t)rr * F_; w = lnw; bp = lnb;
    } else {
        int rr = r - (B_ * N_ + M_);
        src = ctx + (size_t)rr * F_; dst = cn + (size_t)rr * F_; w = lncw; bp = lncb;
    }
    int tid = threadIdx.x;
    int wave = tid >> 6, lane = tid & 63;
    float4 v = reinterpret_cast<const float4*>(src)[tid];
    float s = v.x + v.y + v.z + v.w;
    float sq = v.x * v.x + v.y * v.y + v.z * v.z + v.w * v.w;
    #pragma unroll
    for (int mask = 1; mask < 64; mask <<= 1) {
        s += __shfl_xor(s, mask, 64);
        sq += __shfl_xor(sq, mask, 64);
    }
    __shared__ float red[4];
    if (lane == 0) { red[wave * 2] = s; red[wave * 2 + 1] = sq; }
    __syncthreads();
    float S = red[0] + red[2], SQ = red[1] + red[3];
    float mean = S * (1.0f / F_);
    float var = SQ * (1.0f / F_) - mean * mean;
    float rstd = rsqrtf(var + 1e-5f);
    float4 wv = reinterpret_cast<const float4*>(w)[tid];
    float4 bv = reinterpret_cast<const float4*>(bp)[tid];
    ushort4 o;
    o.x = f32_bf16((v.x - mean) * rstd * wv.x + bv.x);
    o.y = f32_bf16((v.y - mean) * rstd * wv.y + bv.y);
    o.z = f32_bf16((v.z - mean) * rstd * wv.z + bv.z);
    o.w = f32_bf16((v.w - mean) * rstd * wv.w + bv.w);
    reinterpret_cast<ushort4*>(dst)[tid] = o;
}

// ---------------- Weight transpose + f32->bf16: WT[n][k] = W[k][n] --------------
__global__ __launch_bounds__(256) void wtrans_kernel(
    const float* __restrict__ Wq, const float* __restrict__ Wk,
    const float* __restrict__ Wv, const float* __restrict__ Wo,
    ushort* __restrict__ WqT, ushort* __restrict__ WkT,
    ushort* __restrict__ WvT, ushort* __restrict__ WoT)
{
    const float* W; ushort* WT;
    switch (blockIdx.z) {
        case 0: W = Wq; WT = WqT; break;
        case 1: W = Wk; WT = WkT; break;
        case 2: W = Wv; WT = WvT; break;
        default: W = Wo; WT = WoT; break;
    }
    __shared__ float tile[32][33];
    int tx = threadIdx.x, ty = threadIdx.y;   // 32 x 8
    int n0 = blockIdx.x * 32, k0 = blockIdx.y * 32;
    #pragma unroll
    for (int j = 0; j < 4; ++j)
        tile[ty + j * 8][tx] = W[(size_t)(k0 + ty + j * 8) * F_ + n0 + tx];
    __syncthreads();
    #pragma unroll
    for (int j = 0; j < 4; ++j)
        WT[(size_t)(n0 + ty + j * 8) * F_ + k0 + tx] = f32_bf16(tile[tx][ty + j * 8]);
}

// ---------------- bf16 MFMA GEMM: C[R][512] = A[R][512] * B, BT[n][k] given ------
template<bool BIAS, bool OUTF32>
__global__ __launch_bounds__(256) void gemm_kernel(
    const ushort* __restrict__ A, const ushort* __restrict__ BT,
    const float* __restrict__ bias, void* __restrict__ Cout)
{
    __shared__ ushort As[128][72];
    __shared__ ushort Bs[128][72];
    int tid = threadIdx.x;
    int row0 = blockIdx.y * 128;
    int col0 = blockIdx.x * 128;
    int wave = tid >> 6, lane = tid & 63;
    int wm = wave >> 1, wn = wave & 1;
    f32x4 acc[4][4] = {};

    for (int k0 = 0; k0 < F_; k0 += 64) {
        #pragma unroll
        for (int p = 0; p < 4; ++p) {
            int c = tid + p * 256;
            int r = c >> 3, kc = (c & 7) * 8;
            *reinterpret_cast<uint4*>(&As[r][kc]) =
                *reinterpret_cast<const uint4*>(&A[(size_t)(row0 + r) * F_ + k0 + kc]);
            *reinterpret_cast<uint4*>(&Bs[r][kc]) =
                *reinterpret_cast<const uint4*>(&BT[(size_t)(col0 + r) * F_ + k0 + kc]);
        }
        __syncthreads();
        #pragma unroll
        for (int kt = 0; kt < 2; ++kt) {
            int lrow = lane & 15, lk = kt * 32 + (lane >> 4) * 8;
            bf16x8 af[4], bfr[4];
            #pragma unroll
            for (int mt = 0; mt < 4; ++mt)
                af[mt] = *reinterpret_cast<const bf16x8*>(&As[wm * 64 + mt * 16 + lrow][lk]);
            #pragma unroll
            for (int nt = 0; nt < 4; ++nt)
                bfr[nt] = *reinterpret_cast<const bf16x8*>(&Bs[wn * 64 + nt * 16 + lrow][lk]);
            #pragma unroll
            for (int mt = 0; mt < 4; ++mt)
                #pragma unroll
                for (int nt = 0; nt < 4; ++nt)
                    acc[mt][nt] = __builtin_amdgcn_mfma_f32_16x16x32_bf16(
                        af[mt], bfr[nt], acc[mt][nt], 0, 0, 0);
        }
        __syncthreads();
    }

    int lr4 = (lane >> 4) * 4, lc = lane & 15;
    #pragma unroll
    for (int mt = 0; mt < 4; ++mt) {
        #pragma unroll
        for (int nt = 0; nt < 4; ++nt) {
            int ccol = col0 + wn * 64 + nt * 16 + lc;
            float bv = BIAS ? bias[ccol] : 0.0f;
            #pragma unroll
            for (int j = 0; j < 4; ++j) {
                int crow = row0 + wm * 64 + mt * 16 + lr4 + j;
                float val = acc[mt][nt][j] + bv;
                if (OUTF32)
                    reinterpret_cast<float*>(Cout)[(size_t)crow * F_ + ccol] = val;
                else
                    reinterpret_cast<ushort*>(Cout)[(size_t)crow * F_ + ccol] = f32_bf16(val);
            }
        }
    }
}

// ---------------- V transpose: vT[(b*8+h)*64+d][m] = v[b*M+m][h*64+d] ------------
__global__ __launch_bounds__(256) void vtrans_kernel(
    const ushort* __restrict__ v, ushort* __restrict__ vT)
{
    int bh = blockIdx.y;               // b*8+h
    int b = bh >> 3, h = bh & 7;
    int m0 = blockIdx.x * 64;
    __shared__ ushort tile[64][72];
    int tid = threadIdx.x;
    int r = tid >> 2, c8 = (tid & 3) * 16;
    const ushort* vrow = v + (size_t)(b * M_ + m0 + r) * F_ + h * 64 + c8;
    *reinterpret_cast<uint4*>(&tile[r][c8]) = *reinterpret_cast<const uint4*>(&vrow[0]);
    *reinterpret_cast<uint4*>(&tile[r][c8 + 8]) = *reinterpret_cast<const uint4*>(&vrow[8]);
    __syncthreads();
    int d = tid >> 2, mc = (tid & 3) * 16;
    union { ushort u[8]; uint4 q; } p0, p1;
    #pragma unroll
    for (int i = 0; i < 8; ++i) p0.u[i] = tile[mc + i][d];
    #pragma unroll
    for (int i = 0; i < 8; ++i) p1.u[i] = tile[mc + 8 + i][d];
    ushort* orow = vT + ((size_t)bh * 64 + d) * M_ + m0 + mc;
    *reinterpret_cast<uint4*>(&orow[0]) = p0.q;
    *reinterpret_cast<uint4*>(&orow[8]) = p1.q;
}

// ---------------- Flash attention: LDS-staged K/V, 32x32x16 swapped-QK^T ----------
// Block = 4 waves, same (b,h), 128 q-rows. KVBLK=128 staged cooperatively into
// LDS (coalesced 128B transactions, loaded once per block — fixes the scattered
// per-wave loads that were TA/TCP-throughput-bound). Double-buffered LDS + T14
// issue-early/write-late staging regs. XOR bank swizzle on 16B chunks (T2/G4).
// Softmax in-register (swapped QK), P->A-frag via cvt_pk + permlane32_swap.
#define MAKE_PA(dst, p, ss) do {                                               \
    uint32_t w0_, w1_, w2_, w3_;                                               \
    asm("v_cvt_pk_bf16_f32 %0, %1, %2" : "=v"(w0_) : "v"(p[8*(ss)+0]), "v"(p[8*(ss)+1])); \
    asm("v_cvt_pk_bf16_f32 %0, %1, %2" : "=v"(w1_) : "v"(p[8*(ss)+2]), "v"(p[8*(ss)+3])); \
    asm("v_cvt_pk_bf16_f32 %0, %1, %2" : "=v"(w2_) : "v"(p[8*(ss)+4]), "v"(p[8*(ss)+5])); \
    asm("v_cvt_pk_bf16_f32 %0, %1, %2" : "=v"(w3_) : "v"(p[8*(ss)+6]), "v"(p[8*(ss)+7])); \
    asm("v_permlane32_swap_b32 %0, %1" : "+v"(w0_), "+v"(w2_));                \
    asm("v_permlane32_swap_b32 %0, %1" : "+v"(w1_), "+v"(w3_));                \
    union { uint32_t w[4]; bf16x8 v; } u_;                                     \
    u_.w[0] = w0_; u_.w[1] = w1_; u_.w[2] = w2_; u_.w[3] = w3_;                \
    dst = u_.v;                                                                \
} while (0)

// Global -> staging regs for KV tile t (coalesced: 64B/thread contiguous).
#define STAGE_LOAD(t) do {                                                     \
    const ushort* _kp = k + (size_t)((t) * 128 + (tid >> 1)) * F_ + h * 64 + (tid & 1) * 32; \
    _Pragma("unroll")                                                          \
    for (int i_ = 0; i_ < 4; ++i_)                                             \
        kreg[i_] = *reinterpret_cast<const uint4*>(_kp + i_ * 8);              \
    const ushort* _vp = vT + (size_t)(bh * 64 + (tid >> 2)) * M_ + (t) * 128 + (tid & 3) * 32; \
    _Pragma("unroll")                                                          \
    for (int i_ = 0; i_ < 4; ++i_)                                             \
        vreg[i_] = *reinterpret_cast<const uint4*>(_vp + i_ * 8);              \
} while (0)

// Staging regs -> LDS with XOR chunk swizzle.
#define STAGE_WRITE(KLS, VLS) do {                                             \
    int _r = tid >> 1, _c0 = (tid & 1) * 4;                                    \
    _Pragma("unroll")                                                          \
    for (int i_ = 0; i_ < 4; ++i_)                                             \
        KLS[_r][(_c0 + i_) ^ (_r & 7)] = kreg[i_];                             \
    int _d = tid >> 2, _cv = (tid & 3) * 4;                                    \
    _Pragma("unroll")                                                          \
    for (int i_ = 0; i_ < 4; ++i_)                                             \
        VLS[_d][(_cv + i_) ^ (_d & 15)] = vreg[i_];                            \
} while (0)

// One 64-row sub-tile: QK^T from LDS K, online softmax (tree-reduced), PV from LDS V.
#define COMPUTE_SUB(KLS, VLS, s) do {                                          \
    f32x16 sA, sB;                                                             \
    _Pragma("unroll")                                                          \
    for (int j = 0; j < 16; ++j) { sA[j] = 0.0f; sB[j] = 0.0f; }               \
    _Pragma("unroll")                                                          \
    for (int ds_ = 0; ds_ < 4; ++ds_) {                                        \
        bf16x8 kfa = *reinterpret_cast<const bf16x8*>(                         \
            &KLS[(s) * 64 + l31][(ds_ * 2 + g) ^ (l31 & 7)]);                  \
        bf16x8 kfb = *reinterpret_cast<const bf16x8*>(                         \
            &KLS[(s) * 64 + 32 + l31][(ds_ * 2 + g) ^ (l31 & 7)]);             \
        sA = __builtin_amdgcn_mfma_f32_32x32x16_bf16(kfa, qf[ds_], sA, 0, 0, 0); \
        sB = __builtin_amdgcn_mfma_f32_32x32x16_bf16(kfb, qf[ds_], sB, 0, 0, 0); \
    }                                                                          \
    float x0 = fmaxf(sA[0], sB[0]), x1 = fmaxf(sA[1], sB[1]);                  \
    float x2 = fmaxf(sA[2], sB[2]), x3 = fmaxf(sA[3], sB[3]);                  \
    _Pragma("unroll")                                                          \
    for (int j = 4; j < 16; j += 4) {                                          \
        x0 = fmaxf(x0, fmaxf(sA[j], sB[j]));                                   \
        x1 = fmaxf(x1, fmaxf(sA[j + 1], sB[j + 1]));                           \
        x2 = fmaxf(x2, fmaxf(sA[j + 2], sB[j + 2]));                           \
        x3 = fmaxf(x3, fmaxf(sA[j + 3], sB[j + 3]));                           \
    }                                                                          \
    float pm = fmaxf(fmaxf(x0, x1), fmaxf(x2, x3));                            \
    pm = fmaxf(pm, __shfl_xor(pm, 32, 64));                                    \
    pm *= 0.125f;                                                              \
    if (!__all(pm <= m_run + 8.0f)) {                                          \
        float mnew = fmaxf(m_run, pm);                                         \
        float resc = __builtin_amdgcn_exp2f((m_run - mnew) * log2e);           \
        m_run = mnew;                                                          \
        l_run *= resc;                                                         \
        float rf_[16];                                                         \
        _Pragma("unroll")                                                      \
        for (int j = 0; j < 16; ++j)                                           \
            rf_[j] = __shfl(resc, 8 * (j >> 2) + 4 * g + (j & 3), 64);         \
        _Pragma("unroll")                                                      \
        for (int hh = 0; hh < 2; ++hh)                                         \
            _Pragma("unroll")                                                  \
            for (int j = 0; j < 16; ++j) oacc[hh][j] *= rf_[j];                \
    }                                                                          \
    float c2 = -m_run * log2e;                                                 \
    float p0f[16], p1f[16];                                                    \
    _Pragma("unroll")                                                          \
    for (int j = 0; j < 16; ++j)                                               \
        p0f[j] = __builtin_amdgcn_exp2f(fmaf(sA[j], c1, c2));                  \
    _Pragma("unroll")                                                          \
    for (int j = 0; j < 16; ++j)                                               \
        p1f[j] = __builtin_amdgcn_exp2f(fmaf(sB[j], c1, c2));                  \
    float r0 = 0.0f, r1 = 0.0f, r2 = 0.0f, r3 = 0.0f;                          \
    _Pragma("unroll")                                                          \
    for (int j = 0; j < 16; j += 4) {                                          \
        r0 += p0f[j];     r1 += p0f[j + 1];                                    \
        r2 += p0f[j + 2]; r3 += p0f[j + 3];                                    \
    }                                                                          \
    _Pragma("unroll")                                                          \
    for (int j = 0; j < 16; j += 4) {                                          \
        r0 += p1f[j];     r1 += p1f[j + 1];                                    \
        r2 += p1f[j + 2]; r3 += p1f[j + 3];                                    \
    }                                                                          \
    float rs = (r0 + r1) + (r2 + r3);                                          \
    rs += __shfl_xor(rs, 32, 64);                                              \
    l_run += rs;                                                               \
    bf16x8 pa[4];                                                              \
    MAKE_PA(pa[0], p0f, 0);                                                    \
    MAKE_PA(pa[1], p0f, 1);                                                    \
    MAKE_PA(pa[2], p1f, 0);                                                    \
    MAKE_PA(pa[3], p1f, 1);                                                    \
    _Pragma("unroll")                                                          \
    for (int hh = 0; hh < 2; ++hh)                                             \
        _Pragma("unroll")                                                      \
        for (int s_ = 0; s_ < 4; ++s_) {                                       \
            bf16x8 vf = *reinterpret_cast<const bf16x8*>(                      \
                &VLS[hh * 32 + l31][((s) * 8 + s_ * 2 + g) ^ (l31 & 15)]);     \
            oacc[hh] = __builtin_amdgcn_mfma_f32_32x32x16_bf16(                \
                pa[s_], vf, oacc[hh], 0, 0, 0);                                \
        }                                                                      \
} while (0)

__global__ __launch_bounds__(256) void attn_kernel(
    const ushort* __restrict__ q,   // [B*N][512] bf16
    const ushort* __restrict__ k,   // [M][512]   bf16 (batch-independent)
    const ushort* __restrict__ vT,  // [B*H*64][M] bf16
    ushort* __restrict__ o)         // [B*N][512] bf16
{
    const int tid = threadIdx.x;
    const int wave = tid >> 6, lane = tid & 63;
    const int l31 = lane & 31, g = lane >> 5;
    const int bh = blockIdx.y, b = bh >> 3, h = bh & 7;
    const int q0 = blockIdx.x * 128 + wave * 32;

    // LDS double buffers: K [128 rows][8 x 16B chunks], V [64 d][16 x 16B chunks]
    __shared__ uint4 kls0[128][8], kls1[128][8];
    __shared__ uint4 vls0[64][16], vls1[64][16];

    // Q fragments (hoisted): qf[ds] = Q[q0+l31][ds*16 + g*8 .. +7]
    bf16x8 qf[4];
    const ushort* qrow = q + (size_t)(b * N_ + q0 + l31) * F_ + h * 64 + g * 8;
    #pragma unroll
    for (int ds = 0; ds < 4; ++ds)
        qf[ds] = *reinterpret_cast<const bf16x8*>(qrow + ds * 16);

    float m_run = -1e30f, l_run = 0.0f;
    f32x16 oacc[2];
    #pragma unroll
    for (int hh = 0; hh < 2; ++hh)
        #pragma unroll
        for (int j = 0; j < 16; ++j) oacc[hh][j] = 0.0f;

    const float c1 = 0.18033688f;        // 0.125 * log2(e)
    const float log2e = 1.4426950f;

    uint4 kreg[4], vreg[4];
    STAGE_LOAD(0);
    STAGE_WRITE(kls0, vls0);
    STAGE_LOAD(1);
    __syncthreads();

    #pragma unroll 1
    for (int t = 0; t < 16; t += 2) {
        COMPUTE_SUB(kls0, vls0, 0);
        COMPUTE_SUB(kls0, vls0, 1);
        __syncthreads();
        STAGE_WRITE(kls1, vls1);            // tile t+1 (regs already loaded)
        if (t + 2 < 16) STAGE_LOAD(t + 2);
        __syncthreads();
        COMPUTE_SUB(kls1, vls1, 0);
        COMPUTE_SUB(kls1, vls1, 1);
        __syncthreads();
        if (t + 2 < 16) {
            STAGE_WRITE(kls0, vls0);        // tile t+2
            STAGE_LOAD(t + 3);              // t+3 <= 15 whenever t+2 < 16
        }
        __syncthreads();
    }

    // ---- final normalization + store
    float linv = 1.0f / l_run;
    float rf[16];
    #pragma unroll
    for (int j = 0; j < 16; ++j)
        rf[j] = __shfl(linv, 8 * (j >> 2) + 4 * g + (j & 3), 64);
    #pragma unroll
    for (int hh = 0; hh < 2; ++hh)
        #pragma unroll
        for (int j = 0; j < 16; ++j) {
            int qr = (j & 3) + 8 * (j >> 2) + 4 * g;
            o[(size_t)(b * N_ + q0 + qr) * F_ + h * 64 + hh * 32 + l31] =
                f32_bf16(oacc[hh][j] * rf[j]);
        }
}

// ---------------- Launch ---------------------------------------------------------
extern "C" void kernel_launch(void* const* d_in, const int* in_sizes, int n_in,
                              void* d_out, int out_size, void* d_ws, size_t ws_size,
                              hipStream_t stream) {
    const float* x    = (const float*)d_in[0];
    const float* ctx  = (const float*)d_in[1];
    const float* pos  = (const float*)d_in[2];
    const float* lnw  = (const float*)d_in[3];
    const float* lnb  = (const float*)d_in[4];
    const float* lncw = (const float*)d_in[5];
    const float* lncb = (const float*)d_in[6];
    const float* Wq   = (const float*)d_in[7];
    const float* Wk   = (const float*)d_in[8];
    const float* Wv   = (const float*)d_in[9];
    const float* Wo   = (const float*)d_in[10];
    const float* bout = (const float*)d_in[11];
    float* out = (float*)d_out;

    char* ws = (char*)d_ws;
    ushort* xn  = (ushort*)(ws + 0);         // 8 MB  [8192][512]
    ushort* cn  = (ushort*)(ws + 8388608);   // 8 MB  [8192][512]
    ushort* kn  = (ushort*)(ws + 16777216);  // 2 MB  [2048][512]
    ushort* WqT = (ushort*)(ws + 18874368);  // 512 KB
    ushort* WkT = (ushort*)(ws + 19398656);
    ushort* WvT = (ushort*)(ws + 19922944);
    ushort* WoT = (ushort*)(ws + 20447232);
    ushort* qb  = (ushort*)(ws + 20971520);  // 8 MB  [8192][512]
    ushort* kb  = (ushort*)(ws + 29360128);  // 2 MB  [2048][512]
    ushort* vb  = (ushort*)(ws + 31457280);  // 8 MB  [8192][512]
    ushort* vTb = (ushort*)(ws + 39845888);  // 8 MB  [32*64][2048]
    ushort* ao  = (ushort*)(ws + 48234496);  // 8 MB  [8192][512]

    hipLaunchKernelGGL(ln_kernel, dim3(B_ * N_ + M_ + B_ * M_), dim3(128), 0, stream,
                       x, ctx, pos, lnw, lnb, lncw, lncb, xn, kn, cn);
    hipLaunchKernelGGL(wtrans_kernel, dim3(16, 16, 4), dim3(32, 8), 0, stream,
                       Wq, Wk, Wv, Wo, WqT, WkT, WvT, WoT);
    hipLaunchKernelGGL((gemm_kernel<false, false>), dim3(4, 64), dim3(256), 0, stream,
                       xn, WqT, nullptr, (void*)qb);
    hipLaunchKernelGGL((gemm_kernel<false, false>), dim3(4, 16), dim3(256), 0, stream,
                       kn, WkT, nullptr, (void*)kb);
    hipLaunchKernelGGL((gemm_kernel<false, false>), dim3(4, 64), dim3(256), 0, stream,
                       cn, WvT, nullptr, (void*)vb);
    hipLaunchKernelGGL(vtrans_kernel, dim3(32, 32), dim3(256), 0, stream, vb, vTb);
    hipLaunchKernelGGL(attn_kernel, dim3(16, 32), dim3(256), 0, stream, qb, kb, vTb, ao);
    hipLaunchKernelGGL((gemm_kernel<true, true>), dim3(4, 64), dim3(256), 0, stream,
                       ao, WoT, bout, (void*)out);
}

// Round 10
// 132.732 us; speedup vs baseline: 2.2827x; 1.1456x over previous
//
#include <hip/hip_runtime.h>
#include <stdint.h>

#define B_ 4
#define N_ 2048
#define M_ 2048
#define F_ 512
#define H_ 8
#define D_ 64

typedef __bf16 bf16x8 __attribute__((ext_vector_type(8)));
typedef float f32x4 __attribute__((ext_vector_type(4)));
typedef float f32x16 __attribute__((ext_vector_type(16)));

__device__ inline ushort f32_bf16(float f) {
    union { float f; uint32_t u; } v; v.f = f;
    uint32_t r = v.u + 0x7FFFu + ((v.u >> 16) & 1u);
    return (ushort)(r >> 16);
}

// ---------------- LayerNorm: 18432 rows (x: 8192, pos_emb: 2048, context: 8192) ----
__global__ __launch_bounds__(128) void ln_kernel(
    const float* __restrict__ x, const float* __restrict__ ctx, const float* __restrict__ pos,
    const float* __restrict__ lnw, const float* __restrict__ lnb,
    const float* __restrict__ lncw, const float* __restrict__ lncb,
    ushort* __restrict__ xn, ushort* __restrict__ kn, ushort* __restrict__ cn)
{
    int r = blockIdx.x;
    const float* src; ushort* dst; const float* w; const float* bp;
    if (r < B_ * N_) {
        src = x + (size_t)r * F_; dst = xn + (size_t)r * F_; w = lnw; bp = lnb;
    } else if (r < B_ * N_ + M_) {
        int rr = r - B_ * N_;
        src = pos + (size_t)rr * F_; dst = kn + (size_t)rr * F_; w = lnw; bp = lnb;
    } else {
        int rr = r - (B_ * N_ + M_);
        src = ctx + (size_t)rr * F_; dst = cn + (size_t)rr * F_; w = lncw; bp = lncb;
    }
    int tid = threadIdx.x;
    int wave = tid >> 6, lane = tid & 63;
    float4 v = reinterpret_cast<const float4*>(src)[tid];
    float s = v.x + v.y + v.z + v.w;
    float sq = v.x * v.x + v.y * v.y + v.z * v.z + v.w * v.w;
    #pragma unroll
    for (int mask = 1; mask < 64; mask <<= 1) {
        s += __shfl_xor(s, mask, 64);
        sq += __shfl_xor(sq, mask, 64);
    }
    __shared__ float red[4];
    if (lane == 0) { red[wave * 2] = s; red[wave * 2 + 1] = sq; }
    __syncthreads();
    float S = red[0] + red[2], SQ = red[1] + red[3];
    float mean = S * (1.0f / F_);
    float var = SQ * (1.0f / F_) - mean * mean;
    float rstd = rsqrtf(var + 1e-5f);
    float4 wv = reinterpret_cast<const float4*>(w)[tid];
    float4 bv = reinterpret_cast<const float4*>(bp)[tid];
    ushort4 o;
    o.x = f32_bf16((v.x - mean) * rstd * wv.x + bv.x);
    o.y = f32_bf16((v.y - mean) * rstd * wv.y + bv.y);
    o.z = f32_bf16((v.z - mean) * rstd * wv.z + bv.z);
    o.w = f32_bf16((v.w - mean) * rstd * wv.w + bv.w);
    reinterpret_cast<ushort4*>(dst)[tid] = o;
}

// ---------------- Weight transpose + f32->bf16: WT[n][k] = W[k][n] --------------
__global__ __launch_bounds__(256) void wtrans_kernel(
    const float* __restrict__ Wq, const float* __restrict__ Wk,
    const float* __restrict__ Wv, const float* __restrict__ Wo,
    ushort* __restrict__ WqT, ushort* __restrict__ WkT,
    ushort* __restrict__ WvT, ushort* __restrict__ WoT)
{
    const float* W; ushort* WT;
    switch (blockIdx.z) {
        case 0: W = Wq; WT = WqT; break;
        case 1: W = Wk; WT = WkT; break;
        case 2: W = Wv; WT = WvT; break;
        default: W = Wo; WT = WoT; break;
    }
    __shared__ float tile[32][33];
    int tx = threadIdx.x, ty = threadIdx.y;   // 32 x 8
    int n0 = blockIdx.x * 32, k0 = blockIdx.y * 32;
    #pragma unroll
    for (int j = 0; j < 4; ++j)
        tile[ty + j * 8][tx] = W[(size_t)(k0 + ty + j * 8) * F_ + n0 + tx];
    __syncthreads();
    #pragma unroll
    for (int j = 0; j < 4; ++j)
        WT[(size_t)(n0 + ty + j * 8) * F_ + k0 + tx] = f32_bf16(tile[tx][ty + j * 8]);
}

// ---------------- bf16 MFMA GEMM: C[R][512] = A[R][512] * B, BT[n][k] given ------
template<bool BIAS, bool OUTF32>
__global__ __launch_bounds__(256) void gemm_kernel(
    const ushort* __restrict__ A, const ushort* __restrict__ BT,
    const float* __restrict__ bias, void* __restrict__ Cout)
{
    __shared__ ushort As[128][72];
    __shared__ ushort Bs[128][72];
    int tid = threadIdx.x;
    int row0 = blockIdx.y * 128;
    int col0 = blockIdx.x * 128;
    int wave = tid >> 6, lane = tid & 63;
    int wm = wave >> 1, wn = wave & 1;
    f32x4 acc[4][4] = {};

    for (int k0 = 0; k0 < F_; k0 += 64) {
        #pragma unroll
        for (int p = 0; p < 4; ++p) {
            int c = tid + p * 256;
            int r = c >> 3, kc = (c & 7) * 8;
            *reinterpret_cast<uint4*>(&As[r][kc]) =
                *reinterpret_cast<const uint4*>(&A[(size_t)(row0 + r) * F_ + k0 + kc]);
            *reinterpret_cast<uint4*>(&Bs[r][kc]) =
                *reinterpret_cast<const uint4*>(&BT[(size_t)(col0 + r) * F_ + k0 + kc]);
        }
        __syncthreads();
        #pragma unroll
        for (int kt = 0; kt < 2; ++kt) {
            int lrow = lane & 15, lk = kt * 32 + (lane >> 4) * 8;
            bf16x8 af[4], bfr[4];
            #pragma unroll
            for (int mt = 0; mt < 4; ++mt)
                af[mt] = *reinterpret_cast<const bf16x8*>(&As[wm * 64 + mt * 16 + lrow][lk]);
            #pragma unroll
            for (int nt = 0; nt < 4; ++nt)
                bfr[nt] = *reinterpret_cast<const bf16x8*>(&Bs[wn * 64 + nt * 16 + lrow][lk]);
            #pragma unroll
            for (int mt = 0; mt < 4; ++mt)
                #pragma unroll
                for (int nt = 0; nt < 4; ++nt)
                    acc[mt][nt] = __builtin_amdgcn_mfma_f32_16x16x32_bf16(
                        af[mt], bfr[nt], acc[mt][nt], 0, 0, 0);
        }
        __syncthreads();
    }

    int lr4 = (lane >> 4) * 4, lc = lane & 15;
    #pragma unroll
    for (int mt = 0; mt < 4; ++mt) {
        #pragma unroll
        for (int nt = 0; nt < 4; ++nt) {
            int ccol = col0 + wn * 64 + nt * 16 + lc;
            float bv = BIAS ? bias[ccol] : 0.0f;
            #pragma unroll
            for (int j = 0; j < 4; ++j) {
                int crow = row0 + wm * 64 + mt * 16 + lr4 + j;
                float val = acc[mt][nt][j] + bv;
                if (OUTF32)
                    reinterpret_cast<float*>(Cout)[(size_t)crow * F_ + ccol] = val;
                else
                    reinterpret_cast<ushort*>(Cout)[(size_t)crow * F_ + ccol] = f32_bf16(val);
            }
        }
    }
}

// ---------------- K fragment pack: kF[h][t][fk][lane] = A-frag stream -------------
// fk = s*8 + ds*2 + ab; lane l reads kb[t*128 + s*64 + ab*32 + (l&31)][h*64 + ds*16 + (l>>5)*8]
__global__ __launch_bounds__(256) void kpack_kernel(
    const ushort* __restrict__ kb, ushort* __restrict__ kF)
{
    int t = blockIdx.x, h = blockIdx.y;
    int tid = threadIdx.x;
    #pragma unroll
    for (int p = 0; p < 4; ++p) {
        int c = tid + p * 256;              // 0..1023
        int fk = c >> 6, l = c & 63;
        int s = fk >> 3, ds = (fk >> 1) & 3, ab = fk & 1;
        int row = t * 128 + s * 64 + ab * 32 + (l & 31);
        int col = h * 64 + ds * 16 + (l >> 5) * 8;
        uint4 val = *reinterpret_cast<const uint4*>(&kb[(size_t)row * F_ + col]);
        *reinterpret_cast<uint4*>(
            &kF[(((size_t)(h * 16 + t) * 16 + fk) * 64 + l) * 8]) = val;
    }
}

// ---------------- V fragment pack (transpose + frag layout in one) ----------------
// vF[bh][t][fv][lane], fv = hh*8 + s*4 + s_; lane l holds
// V^T[d = hh*32+(l&31)][m = t*128 + s*64 + s_*16 + (l>>5)*8 .. +7]
__global__ __launch_bounds__(256) void vpack_kernel(
    const ushort* __restrict__ v, ushort* __restrict__ vF)
{
    int bh = blockIdx.y;               // b*8+h
    int b = bh >> 3, h = bh & 7;
    int m0 = blockIdx.x * 64;
    int t = blockIdx.x >> 1, s = blockIdx.x & 1;
    __shared__ ushort tile[64][72];    // [m_local][d]
    int tid = threadIdx.x;
    int r = tid >> 2, c8 = (tid & 3) * 16;
    const ushort* vrow = v + (size_t)(b * M_ + m0 + r) * F_ + h * 64 + c8;
    *reinterpret_cast<uint4*>(&tile[r][c8]) = *reinterpret_cast<const uint4*>(&vrow[0]);
    *reinterpret_cast<uint4*>(&tile[r][c8 + 8]) = *reinterpret_cast<const uint4*>(&vrow[8]);
    __syncthreads();
    #pragma unroll
    for (int p = 0; p < 2; ++p) {
        int c = tid + p * 256;             // 0..511
        int fvl = c >> 6, l = c & 63;      // fvl: hh*4 + s_
        int hh = fvl >> 2, s_ = fvl & 3;
        int d = hh * 32 + (l & 31);
        int mloc = s_ * 16 + (l >> 5) * 8;
        union { ushort u[8]; uint4 q; } tmp;
        #pragma unroll
        for (int i = 0; i < 8; ++i) tmp.u[i] = tile[mloc + i][d];
        int fv = hh * 8 + s * 4 + s_;
        *reinterpret_cast<uint4*>(
            &vF[(((size_t)(bh * 16 + t) * 16 + fv) * 64 + l) * 8]) = tmp.q;
    }
}

// ---------------- Flash attention: fragment streams, no LDS, no barriers ----------
// All K/V loads are lane-consecutive 16B (one 1KB transaction per instruction).
// Swapped QK^T (S^T = mfma(K,Q)), in-register softmax, cvt_pk+permlane P->A.
// K prefetched one sub-tile ahead (register dbuf); V preloaded per sub.
#define MAKE_PA(dst, p, ss) do {                                               \
    uint32_t w0_, w1_, w2_, w3_;                                               \
    asm("v_cvt_pk_bf16_f32 %0, %1, %2" : "=v"(w0_) : "v"(p[8*(ss)+0]), "v"(p[8*(ss)+1])); \
    asm("v_cvt_pk_bf16_f32 %0, %1, %2" : "=v"(w1_) : "v"(p[8*(ss)+2]), "v"(p[8*(ss)+3])); \
    asm("v_cvt_pk_bf16_f32 %0, %1, %2" : "=v"(w2_) : "v"(p[8*(ss)+4]), "v"(p[8*(ss)+5])); \
    asm("v_cvt_pk_bf16_f32 %0, %1, %2" : "=v"(w3_) : "v"(p[8*(ss)+6]), "v"(p[8*(ss)+7])); \
    asm("v_permlane32_swap_b32 %0, %1" : "+v"(w0_), "+v"(w2_));                \
    asm("v_permlane32_swap_b32 %0, %1" : "+v"(w1_), "+v"(w3_));                \
    union { uint32_t w[4]; bf16x8 v; } u_;                                     \
    u_.w[0] = w0_; u_.w[1] = w1_; u_.w[2] = w2_; u_.w[3] = w3_;                \
    dst = u_.v;                                                                \
} while (0)

// K frags for sub u: contiguous 8 frags at u*4096.
#define KLOAD(DST, u) do {                                                     \
    const ushort* _p = kfb_ + (size_t)(u) * 4096 + lane * 8;                   \
    _Pragma("unroll")                                                          \
    for (int f_ = 0; f_ < 8; ++f_)                                             \
        DST[f_] = *reinterpret_cast<const bf16x8*>(_p + f_ * 512);             \
} while (0)

// V frags for sub u (t=u>>1, s=u&1): frag fv = hh*8 + s*4 + s_.
#define VLOAD(DST, u) do {                                                     \
    const ushort* _p = vfb_ + (size_t)((u) >> 1) * 8192 +                      \
                       ((u) & 1) * 4 * 512 + lane * 8;                         \
    _Pragma("unroll")                                                          \
    for (int hh_ = 0; hh_ < 2; ++hh_)                                          \
        _Pragma("unroll")                                                      \
        for (int s2_ = 0; s2_ < 4; ++s2_)                                      \
            DST[hh_ * 4 + s2_] = *reinterpret_cast<const bf16x8*>(             \
                _p + (hh_ * 8 + s2_) * 512);                                   \
} while (0)

#define COMPUTE(KR, VR) do {                                                   \
    f32x16 sA, sB;                                                             \
    _Pragma("unroll")                                                          \
    for (int j = 0; j < 16; ++j) { sA[j] = 0.0f; sB[j] = 0.0f; }               \
    _Pragma("unroll")                                                          \
    for (int ds_ = 0; ds_ < 4; ++ds_) {                                        \
        sA = __builtin_amdgcn_mfma_f32_32x32x16_bf16(KR[ds_ * 2], qf[ds_], sA, 0, 0, 0); \
        sB = __builtin_amdgcn_mfma_f32_32x32x16_bf16(KR[ds_ * 2 + 1], qf[ds_], sB, 0, 0, 0); \
    }                                                                          \
    float x0 = fmaxf(sA[0], sB[0]), x1 = fmaxf(sA[1], sB[1]);                  \
    float x2 = fmaxf(sA[2], sB[2]), x3 = fmaxf(sA[3], sB[3]);                  \
    _Pragma("unroll")                                                          \
    for (int j = 4; j < 16; j += 4) {                                          \
        x0 = fmaxf(x0, fmaxf(sA[j], sB[j]));                                   \
        x1 = fmaxf(x1, fmaxf(sA[j + 1], sB[j + 1]));                           \
        x2 = fmaxf(x2, fmaxf(sA[j + 2], sB[j + 2]));                           \
        x3 = fmaxf(x3, fmaxf(sA[j + 3], sB[j + 3]));                           \
    }                                                                          \
    float pm = fmaxf(fmaxf(x0, x1), fmaxf(x2, x3));                            \
    pm = fmaxf(pm, __shfl_xor(pm, 32, 64));                                    \
    pm *= 0.125f;                                                              \
    if (!__all(pm <= m_run + 8.0f)) {                                          \
        float mnew = fmaxf(m_run, pm);                                         \
        float resc = __builtin_amdgcn_exp2f((m_run - mnew) * log2e);           \
        m_run = mnew;                                                          \
        l_run *= resc;                                                         \
        float rf_[16];                                                         \
        _Pragma("unroll")                                                      \
        for (int j = 0; j < 16; ++j)                                           \
            rf_[j] = __shfl(resc, 8 * (j >> 2) + 4 * g + (j & 3), 64);         \
        _Pragma("unroll")                                                      \
        for (int hh = 0; hh < 2; ++hh)                                         \
            _Pragma("unroll")                                                  \
            for (int j = 0; j < 16; ++j) oacc[hh][j] *= rf_[j];                \
    }                                                                          \
    float c2 = -m_run * log2e;                                                 \
    float p0f[16], p1f[16];                                                    \
    _Pragma("unroll")                                                          \
    for (int j = 0; j < 16; ++j)                                               \
        p0f[j] = __builtin_amdgcn_exp2f(fmaf(sA[j], c1, c2));                  \
    _Pragma("unroll")                                                          \
    for (int j = 0; j < 16; ++j)                                               \
        p1f[j] = __builtin_amdgcn_exp2f(fmaf(sB[j], c1, c2));                  \
    float r0 = 0.0f, r1 = 0.0f, r2 = 0.0f, r3 = 0.0f;                          \
    _Pragma("unroll")                                                          \
    for (int j = 0; j < 16; j += 4) {                                          \
        r0 += p0f[j];     r1 += p0f[j + 1];                                    \
        r2 += p0f[j + 2]; r3 += p0f[j + 3];                                    \
    }                                                                          \
    _Pragma("unroll")                                                          \
    for (int j = 0; j < 16; j += 4) {                                          \
        r0 += p1f[j];     r1 += p1f[j + 1];                                    \
        r2 += p1f[j + 2]; r3 += p1f[j + 3];                                    \
    }                                                                          \
    float rs = (r0 + r1) + (r2 + r3);                                          \
    rs += __shfl_xor(rs, 32, 64);                                              \
    l_run += rs;                                                               \
    bf16x8 pa[4];                                                              \
    MAKE_PA(pa[0], p0f, 0);                                                    \
    MAKE_PA(pa[1], p0f, 1);                                                    \
    MAKE_PA(pa[2], p1f, 0);                                                    \
    MAKE_PA(pa[3], p1f, 1);                                                    \
    _Pragma("unroll")                                                          \
    for (int hh = 0; hh < 2; ++hh)                                             \
        _Pragma("unroll")                                                      \
        for (int s_ = 0; s_ < 4; ++s_)                                         \
            oacc[hh] = __builtin_amdgcn_mfma_f32_32x32x16_bf16(                \
                pa[s_], VR[hh * 4 + s_], oacc[hh], 0, 0, 0);                   \
} while (0)

__global__ __launch_bounds__(256) void attn_kernel(
    const ushort* __restrict__ q,   // [B*N][512] bf16
    const ushort* __restrict__ kF,  // [H][16][16 frag][64 lane][8] bf16
    const ushort* __restrict__ vF,  // [B*H][16][16 frag][64 lane][8] bf16
    ushort* __restrict__ o)         // [B*N][512] bf16
{
    const int wave = threadIdx.x >> 6, lane = threadIdx.x & 63;
    const int l31 = lane & 31, g = lane >> 5;
    const int bh = blockIdx.y, b = bh >> 3, h = bh & 7;
    const int q0 = blockIdx.x * 128 + wave * 32;

    // Q fragments (hoisted)
    bf16x8 qf[4];
    const ushort* qrow = q + (size_t)(b * N_ + q0 + l31) * F_ + h * 64 + g * 8;
    #pragma unroll
    for (int ds = 0; ds < 4; ++ds)
        qf[ds] = *reinterpret_cast<const bf16x8*>(qrow + ds * 16);

    float m_run = -1e30f, l_run = 0.0f;
    f32x16 oacc[2];
    #pragma unroll
    for (int hh = 0; hh < 2; ++hh)
        #pragma unroll
        for (int j = 0; j < 16; ++j) oacc[hh][j] = 0.0f;

    const ushort* kfb_ = kF + (size_t)h * 16 * 16 * 512;
    const ushort* vfb_ = vF + (size_t)bh * 16 * 16 * 512;
    const float c1 = 0.18033688f;        // 0.125 * log2(e)
    const float log2e = 1.4426950f;

    bf16x8 kA[8], kB[8], vvA[8], vvB[8];
    KLOAD(kA, 0);

    #pragma unroll 1
    for (int u = 0; u < 32; u += 2) {
        VLOAD(vvA, u);
        KLOAD(kB, u + 1);
        COMPUTE(kA, vvA);
        VLOAD(vvB, u + 1);
        if (u + 2 < 32) KLOAD(kA, u + 2);
        COMPUTE(kB, vvB);
    }

    // ---- final normalization + store
    float linv = 1.0f / l_run;
    float rf[16];
    #pragma unroll
    for (int j = 0; j < 16; ++j)
        rf[j] = __shfl(linv, 8 * (j >> 2) + 4 * g + (j & 3), 64);
    #pragma unroll
    for (int hh = 0; hh < 2; ++hh)
        #pragma unroll
        for (int j = 0; j < 16; ++j) {
            int qr = (j & 3) + 8 * (j >> 2) + 4 * g;
            o[(size_t)(b * N_ + q0 + qr) * F_ + h * 64 + hh * 32 + l31] =
                f32_bf16(oacc[hh][j] * rf[j]);
        }
}

// ---------------- Launch ---------------------------------------------------------
extern "C" void kernel_launch(void* const* d_in, const int* in_sizes, int n_in,
                              void* d_out, int out_size, void* d_ws, size_t ws_size,
                              hipStream_t stream) {
    const float* x    = (const float*)d_in[0];
    const float* ctx  = (const float*)d_in[1];
    const float* pos  = (const float*)d_in[2];
    const float* lnw  = (const float*)d_in[3];
    const float* lnb  = (const float*)d_in[4];
    const float* lncw = (const float*)d_in[5];
    const float* lncb = (const float*)d_in[6];
    const float* Wq   = (const float*)d_in[7];
    const float* Wk   = (const float*)d_in[8];
    const float* Wv   = (const float*)d_in[9];
    const float* Wo   = (const float*)d_in[10];
    const float* bout = (const float*)d_in[11];
    float* out = (float*)d_out;

    char* ws = (char*)d_ws;
    ushort* xn  = (ushort*)(ws + 0);         // 8 MB  [8192][512]
    ushort* cn  = (ushort*)(ws + 8388608);   // 8 MB  [8192][512]
    ushort* kn  = (ushort*)(ws + 16777216);  // 2 MB  [2048][512] -> reused as kF
    ushort* WqT = (ushort*)(ws + 18874368);  // 512 KB
    ushort* WkT = (ushort*)(ws + 19398656);
    ushort* WvT = (ushort*)(ws + 19922944);
    ushort* WoT = (ushort*)(ws + 20447232);
    ushort* qb  = (ushort*)(ws + 20971520);  // 8 MB  [8192][512]
    ushort* kb  = (ushort*)(ws + 29360128);  // 2 MB  [2048][512]
    ushort* vb  = (ushort*)(ws + 31457280);  // 8 MB  [8192][512]
    ushort* vFb = (ushort*)(ws + 39845888);  // 8 MB  frag-packed V
    ushort* ao  = (ushort*)(ws + 48234496);  // 8 MB  [8192][512]
    ushort* kFb = kn;                        // kn slot free after gemm-k consumes it

    hipLaunchKernelGGL(ln_kernel, dim3(B_ * N_ + M_ + B_ * M_), dim3(128), 0, stream,
                       x, ctx, pos, lnw, lnb, lncw, lncb, xn, kn, cn);
    hipLaunchKernelGGL(wtrans_kernel, dim3(16, 16, 4), dim3(32, 8), 0, stream,
                       Wq, Wk, Wv, Wo, WqT, WkT, WvT, WoT);
    hipLaunchKernelGGL((gemm_kernel<false, false>), dim3(4, 64), dim3(256), 0, stream,
                       xn, WqT, nullptr, (void*)qb);
    hipLaunchKernelGGL((gemm_kernel<false, false>), dim3(4, 16), dim3(256), 0, stream,
                       kn, WkT, nullptr, (void*)kb);
    hipLaunchKernelGGL((gemm_kernel<false, false>), dim3(4, 64), dim3(256), 0, stream,
                       cn, WvT, nullptr, (void*)vb);
    hipLaunchKernelGGL(kpack_kernel, dim3(16, 8), dim3(256), 0, stream, kb, kFb);
    hipLaunchKernelGGL(vpack_kernel, dim3(32, 32), dim3(256), 0, stream, vb, vFb);
    hipLaunchKernelGGL(attn_kernel, dim3(16, 32), dim3(256), 0, stream, qb, kFb, vFb, ao);
    hipLaunchKernelGGL((gemm_kernel<true, true>), dim3(4, 64), dim3(256), 0, stream,
                       ao, WoT, bout, (void*)out);
}